// Round 15
// baseline (174.521 us; speedup 1.0000x reference)
//
#include <hip/hip_runtime.h>
#include <math.h>

typedef float f4 __attribute__((ext_vector_type(4)));
typedef float f2 __attribute__((ext_vector_type(2)));

#define L_LEN 2048
#define C_DIM 96
#define N_DIM 16
#define R_DIM 6
#define G_DIM 12
#define B_DIM 4
#define NCHUNK 64
#define CLEN 32
#define BGC (B_DIM * G_DIM * C_DIM) // 4608

// workspace layout (floats)
#define SZ_DELTA (B_DIM * G_DIM * L_LEN * C_DIM) // 9437184
#define SZ_DTS8 (B_DIM * G_DIM * L_LEN * 8)      // 786432
#define SZ_BC (B_DIM * G_DIM * N_DIM * L_LEN)    // 1572864
#define SZ_U6 (B_DIM * 6 * C_DIM * L_LEN)        // 4718592
#define SZ_Y (B_DIM * G_DIM * C_DIM * L_LEN)     // 9437184
#define SZ_H (BGC * NCHUNK * N_DIM)              // 4718592
#define SZ_S (BGC * NCHUNK)                      // 294912
#define SZ_X (B_DIM * 2 * C_DIM * 1024)          // 786432

__device__ __forceinline__ float fexp2(float x) { return __builtin_amdgcn_exp2f(x); }
__device__ __forceinline__ f2 pkfma(f2 a, f2 b, f2 c) { return __builtin_elementwise_fma(a, b, c); }

__device__ __forceinline__ float softplus_f(float x)
{
    float sp = __logf(1.f + __expf(x));
    return (x > 20.f) ? x : sp;
}

// ---------------- K0: transpose x (H<->W) for odd-k coalescing ----------------
__global__ __launch_bounds__(256) void k0_xT(
    const float* __restrict__ x, float* __restrict__ xT)
{
    __shared__ float t[32][33];
    int img = blockIdx.x;
    const float* src = x + (size_t)img * 1024;
    float* dst = xT + (size_t)img * 1024;
    int tx = threadIdx.x & 31, ty = threadIdx.x >> 5;
#pragma unroll
    for (int r = 0; r < 32; r += 8) t[ty + r][tx] = src[(ty + r) * 32 + tx];
    __syncthreads();
#pragma unroll
    for (int r = 0; r < 32; r += 8) dst[(ty + r) * 32 + tx] = t[tx][ty + r];
}

// ---------------- K0b: zero-pad x_proj_weight rows 38->40 ----------------
__global__ __launch_bounds__(256) void k0b_padw(
    const float* __restrict__ xpw, float* __restrict__ wpad)
{
    int i = blockIdx.x * 256 + (int)threadIdx.x;
    if (i >= G_DIM * 40 * C_DIM) return;
    int g = i / (40 * C_DIM);
    int rem = i - g * 40 * C_DIM;
    int p = rem / C_DIM, c = rem - (rem / C_DIM) * C_DIM;
    wpad[i] = (p < 38) ? xpw[((size_t)g * 38 + p) * C_DIM + c] : 0.f;
}

// ---------------- K1: paired cross-scan gather + projections ----------------
// Outputs: dts8 [bg][l][8], B/C [bg][l][16], u6T [b6g][l][c]. (delta moved to k1b)
__global__ __launch_bounds__(256) void k1_proj(
    const float* __restrict__ x, const float* __restrict__ xT,
    const float* __restrict__ wpad,
    float* __restrict__ dts8, float* __restrict__ Bsw,
    float* __restrict__ Csw, float* __restrict__ u6T)
{
    __shared__ float Vsh[C_DIM * 68];
    __shared__ float Psh[40][68];

    int blk = blockIdx.x;
    int ltile = blk & 31;
    int bks = blk >> 5;
    int s = bks % 3;
    int k = (bks / 3) & 1;
    int b = bks / 6;
    int g = k * 3 + s;
    int gh = g + 6;
    int l0 = ltile * 64;
    int l0h = (31 - ltile) * 64;
    int bg = b * G_DIM + g;
    int bgh = b * G_DIM + gh;
    int tid = (int)threadIdx.x;

    const float* xb = (k ? xT : x) + (size_t)b * 2 * C_DIM * 1024;

#pragma unroll
    for (int j = 0; j < 6; ++j) {
        int e = tid + j * 256;
        int c = e >> 4;
        int llq = (e & 15) * 4;
        int pp = (l0 + llq) >> 1;
        f2 x0 = *(const f2*)(xb + (size_t)c * 1024 + pp);
        f2 x1 = *(const f2*)(xb + (size_t)(C_DIM + c) * 1024 + pp);
        f4 v;
        if (s == 2)      { v[0] = x0.x; v[1] = x1.x; v[2] = x0.y; v[3] = x1.y; }
        else if (s == 1) { v[0] = x1.x - x0.x; v[1] = x1.x; v[2] = x1.y - x0.y; v[3] = x1.y; }
        else             { v[0] = x0.x - x1.x; v[1] = x0.x; v[2] = x0.y - x1.y; v[3] = x0.y; }
        *(f4*)(Vsh + c * 68 + llq) = v;
    }
    __syncthreads();

    {
        size_t ub = ((size_t)(b * 6 + g) * L_LEN + l0) * C_DIM;
#pragma unroll
        for (int j = 0; j < 6; ++j) {
            int e = tid + j * 256;
            int lidx = e / 24;
            int c4 = (e - lidx * 24) * 4;
            f4 v = { Vsh[(c4 + 0) * 68 + lidx], Vsh[(c4 + 1) * 68 + lidx],
                     Vsh[(c4 + 2) * 68 + lidx], Vsh[(c4 + 3) * 68 + lidx] };
            *(f4*)(u6T + ub + (size_t)lidx * C_DIM + c4) = v;
        }
    }

    int ll = tid & 63;
    int P0 = __builtin_amdgcn_readfirstlane((tid >> 6) * 10);
    const float* wp = wpad + (size_t)g * 3840 + (size_t)P0 * C_DIM;
    const float* wph = wpad + (size_t)gh * 3840 + (size_t)P0 * C_DIM;

    float acc[10], acch[10];
#pragma unroll
    for (int p = 0; p < 10; ++p) { acc[p] = 0.f; acch[p] = 0.f; }

    for (int cb = 0; cb < C_DIM; cb += 8) {
        float vc[8], vch[8];
#pragma unroll
        for (int i = 0; i < 8; ++i) {
            vc[i] = Vsh[(cb + i) * 68 + ll];
            vch[i] = Vsh[(cb + i) * 68 + 63 - ll];
        }
#pragma unroll
        for (int p = 0; p < 10; ++p) {
#pragma unroll
            for (int q = 0; q < 2; ++q) {
                f4 w = *(const f4*)(wp + p * C_DIM + cb + q * 4);
                f4 wh = *(const f4*)(wph + p * C_DIM + cb + q * 4);
#pragma unroll
                for (int i = 0; i < 4; ++i) {
                    acc[p] = fmaf(w[i], vc[q * 4 + i], acc[p]);
                    acch[p] = fmaf(wh[i], vch[q * 4 + i], acch[p]);
                }
            }
        }
    }

#pragma unroll
    for (int gg = 0; gg < 2; ++gg) {
        __syncthreads();
#pragma unroll
        for (int p = 0; p < 10; ++p) Psh[P0 + p][ll] = gg ? acch[p] : acc[p];
        __syncthreads();
        int lb = gg ? l0h : l0;
        int bgx = gg ? bgh : bg;
        int q = tid & 3, lx = tid >> 2;
        f4 bv = { Psh[6 + q * 4 + 0][lx], Psh[6 + q * 4 + 1][lx],
                  Psh[6 + q * 4 + 2][lx], Psh[6 + q * 4 + 3][lx] };
        *(f4*)(Bsw + ((size_t)bgx * L_LEN + lb + lx) * N_DIM + q * 4) = bv;
        f4 cv = { Psh[22 + q * 4 + 0][lx], Psh[22 + q * 4 + 1][lx],
                  Psh[22 + q * 4 + 2][lx], Psh[22 + q * 4 + 3][lx] };
        *(f4*)(Csw + ((size_t)bgx * L_LEN + lb + lx) * N_DIM + q * 4) = cv;
        // dts rows for k1b (stride 8 for aligned vector loads)
#pragma unroll
        for (int e = tid; e < 64 * 8; e += 256) {
            int lx2 = e >> 3, r = e & 7;
            dts8[((size_t)bgx * L_LEN + lb + lx2) * 8 + r] = (r < 6) ? Psh[r][lx2] : 0.f;
        }
    }
}

// ---------------- K1b: delta = softplus(bias + dts.wd), streaming ----------------
__global__ __launch_bounds__(256) void k1b_delta(
    const float* __restrict__ dts8, const float* __restrict__ dtw,
    const float* __restrict__ dtb, float* __restrict__ deltaT)
{
    __shared__ float Dsh[64 * 8];
    int blk = blockIdx.x;              // bg*32 + ltile
    int ltile = blk & 31;
    int bg = blk >> 5;
    int g = bg % G_DIM;
    int l0 = ltile * 64;
    int tid = (int)threadIdx.x;

    const f4* Dg = (const f4*)(dts8 + ((size_t)bg * L_LEN + l0) * 8);
    if (tid < 128) ((f4*)Dsh)[tid] = Dg[tid];
    __syncthreads();

    const float* wdg = dtw + (size_t)g * C_DIM * R_DIM;
    const float* biasg = dtb + g * C_DIM;
    size_t db = ((size_t)bg * L_LEN + l0) * C_DIM;
#pragma unroll
    for (int it = 0; it < 24; ++it) {
        int e = tid + it * 256;
        int lidx = e / 96, c = e - (e / 96) * 96;
        const float* wrow = wdg + c * R_DIM;
        float dsum = biasg[c];
#pragma unroll
        for (int r = 0; r < R_DIM; ++r) dsum = fmaf(Dsh[lidx * 8 + r], wrow[r], dsum);
        deltaT[db + (size_t)lidx * C_DIM + c] = softplus_f(dsum);
    }
}

// ---------------- K2: chunk-parallel scan, channel-paired, full grid ----------------
// block = 96 thr = 48 c-pairs x 2 chunk-slots; window 64 l; grid 1536.
__global__ __launch_bounds__(96) void k2_scanA(
    const float* __restrict__ deltaT, const float* __restrict__ Bsw,
    const float* __restrict__ u6T, const float* __restrict__ A_logs,
    float* __restrict__ hend, float* __restrict__ Sbuf)
{
    __shared__ f4 Bsh[256];     // 64 l x 16 n
    int blk = blockIdx.x;
    int chgrp = blk & 31;
    int bg = blk >> 5;
    int g = bg % G_DIM;
    int b = bg / G_DIM;
    int tid = (int)threadIdx.x;

    const f4* Bg = (const f4*)(Bsw + ((size_t)bg * L_LEN + chgrp * 64) * N_DIM);
    for (int i = tid; i < 256; i += 96) Bsh[i] = Bg[i];
    __syncthreads();

    int chl = tid / 48;          // 0..1
    int cp = tid % 48;
    int c0 = cp * 2;
    int ch = chgrp * 2 + chl;
    const bool rev = (g >= 6);
    int gu = rev ? (g - 6) : g;

    f2 a2[N_DIM];
    {
        const f4* A0 = (const f4*)(A_logs + ((size_t)g * C_DIM + c0) * N_DIM);
        const f4* A1 = (const f4*)(A_logs + ((size_t)g * C_DIM + c0 + 1) * N_DIM);
#pragma unroll
        for (int q = 0; q < 4; ++q) {
            f4 v0 = A0[q], v1 = A1[q];
#pragma unroll
            for (int i = 0; i < 4; ++i)
                a2[q * 4 + i] = (f2){ -__expf(v0[i]) * 1.44269504f, -__expf(v1[i]) * 1.44269504f };
        }
    }

    const int LOFF = ch * CLEN;
    const float* dp = deltaT + ((size_t)bg * L_LEN + LOFF) * C_DIM + c0;
    const float* up;
    int us;
    if (rev) { up = u6T + ((size_t)(b * 6 + gu) * L_LEN + (2047 - LOFF)) * C_DIM + c0; us = -C_DIM; }
    else     { up = u6T + ((size_t)(b * 6 + gu) * L_LEN + LOFF) * C_DIM + c0; us = C_DIM; }

    f2 h2[N_DIM];
#pragma unroll
    for (int n = 0; n < N_DIM; ++n) h2[n] = (f2){0.f, 0.f};
    f2 S2 = {0.f, 0.f};

    f2 dbuf[2], ubuf[2];
#pragma unroll
    for (int j = 0; j < 2; ++j) { dbuf[j] = *(const f2*)(dp + j * C_DIM); ubuf[j] = *(const f2*)(up + j * us); }

    for (int jj = 0; jj < CLEN; jj += 2) {
        int nx = (jj + 2 < CLEN) ? jj + 2 : jj;
        f2 dn[2], un[2];
#pragma unroll
        for (int j = 0; j < 2; ++j) { dn[j] = *(const f2*)(dp + (nx + j) * C_DIM); un[j] = *(const f2*)(up + (nx + j) * us); }
#pragma unroll
        for (int j = 0; j < 2; ++j) {
            int li = chl * CLEN + jj + j;
            f2 dv = dbuf[j];
            S2 += dv;
            f2 du2 = dv * ubuf[j];
            const f4* Bl = Bsh + (size_t)li * 4;
#pragma unroll
            for (int q = 0; q < 4; ++q) {
                f4 Bq = Bl[q];
#pragma unroll
                for (int i = 0; i < 4; ++i) {
                    int n = q * 4 + i;
                    f2 m = dv * a2[n];
                    f2 e = { fexp2(m.x), fexp2(m.y) };
                    h2[n] = pkfma(h2[n], e, du2 * (f2){Bq[i], Bq[i]});
                }
            }
        }
#pragma unroll
        for (int j = 0; j < 2; ++j) { dbuf[j] = dn[j]; ubuf[j] = un[j]; }
    }
    size_t base0 = ((size_t)(bg * C_DIM + c0) * NCHUNK + ch) * N_DIM;
    size_t base1 = base0 + (size_t)NCHUNK * N_DIM;
#pragma unroll
    for (int q = 0; q < 4; ++q) {
        f4 h0 = { h2[q * 4].x, h2[q * 4 + 1].x, h2[q * 4 + 2].x, h2[q * 4 + 3].x };
        f4 h1 = { h2[q * 4].y, h2[q * 4 + 1].y, h2[q * 4 + 2].y, h2[q * 4 + 3].y };
        *(f4*)(hend + base0 + q * 4) = h0;
        *(f4*)(hend + base1 + q * 4) = h1;
    }
    Sbuf[(size_t)(bg * C_DIM + c0) * NCHUNK + ch] = S2.x;
    Sbuf[(size_t)(bg * C_DIM + c0 + 1) * NCHUNK + ch] = S2.y;
}

// Pass B: compose chunk propagators; hend -> hstart IN PLACE (P recomputed from S).
__global__ __launch_bounds__(256) void k2_fix(
    const float* __restrict__ Sbuf, const float* __restrict__ A_logs, float* hh)
{
    int t = blockIdx.x * 256 + (int)threadIdx.x; // 73728
    int n = t & 15;
    int bgc = t >> 4;
    int c = bgc % C_DIM;
    int g = (bgc / C_DIM) % G_DIM;
    float a2 = -__expf(A_logs[((size_t)g * C_DIM + c) * N_DIM + n]) * 1.44269504f;
    const float* Sp = Sbuf + (size_t)bgc * NCHUNK;
    float h = 0.f;
    for (int ch = 0; ch < NCHUNK; ++ch) {
        size_t idx = ((size_t)bgc * NCHUNK + ch) * N_DIM + n;
        float he = hh[idx];
        float P = fexp2(a2 * Sp[ch]);
        hh[idx] = h;
        h = fmaf(h, P, he);
    }
}

// Pass C: exact recurrence from hstart, channel-paired, writes yT (+Ds*u folded).
__global__ __launch_bounds__(96) void k2_scanC(
    const float* __restrict__ deltaT, const float* __restrict__ Bsw,
    const float* __restrict__ Csw, const float* __restrict__ u6T,
    const float* __restrict__ A_logs, const float* __restrict__ Ds,
    const float* __restrict__ hstart, float* __restrict__ yssT)
{
    __shared__ f4 Bsh[256];
    __shared__ f4 Csh[256];
    int blk = blockIdx.x;
    int chgrp = blk & 31;
    int bg = blk >> 5;
    int g = bg % G_DIM;
    int b = bg / G_DIM;
    int tid = (int)threadIdx.x;

    const f4* Bg = (const f4*)(Bsw + ((size_t)bg * L_LEN + chgrp * 64) * N_DIM);
    const f4* Cg = (const f4*)(Csw + ((size_t)bg * L_LEN + chgrp * 64) * N_DIM);
    for (int i = tid; i < 256; i += 96) { Bsh[i] = Bg[i]; Csh[i] = Cg[i]; }
    __syncthreads();

    int chl = tid / 48;
    int cp = tid % 48;
    int c0 = cp * 2;
    int ch = chgrp * 2 + chl;
    const bool rev = (g >= 6);
    int gu = rev ? (g - 6) : g;

    f2 a2[N_DIM];
    {
        const f4* A0 = (const f4*)(A_logs + ((size_t)g * C_DIM + c0) * N_DIM);
        const f4* A1 = (const f4*)(A_logs + ((size_t)g * C_DIM + c0 + 1) * N_DIM);
#pragma unroll
        for (int q = 0; q < 4; ++q) {
            f4 v0 = A0[q], v1 = A1[q];
#pragma unroll
            for (int i = 0; i < 4; ++i)
                a2[q * 4 + i] = (f2){ -__expf(v0[i]) * 1.44269504f, -__expf(v1[i]) * 1.44269504f };
        }
    }
    f2 dsc = *(const f2*)(Ds + g * C_DIM + c0);

    const int LOFF = ch * CLEN;
    const float* dp = deltaT + ((size_t)bg * L_LEN + LOFF) * C_DIM + c0;
    const float* up;
    int us;
    if (rev) { up = u6T + ((size_t)(b * 6 + gu) * L_LEN + (2047 - LOFF)) * C_DIM + c0; us = -C_DIM; }
    else     { up = u6T + ((size_t)(b * 6 + gu) * L_LEN + LOFF) * C_DIM + c0; us = C_DIM; }
    float* yp = yssT + ((size_t)bg * L_LEN + LOFF) * C_DIM + c0;

    f2 h2[N_DIM];
    {
        size_t base0 = ((size_t)(bg * C_DIM + c0) * NCHUNK + ch) * N_DIM;
        size_t base1 = base0 + (size_t)NCHUNK * N_DIM;
#pragma unroll
        for (int q = 0; q < 4; ++q) {
            f4 h0 = *(const f4*)(hstart + base0 + q * 4);
            f4 h1 = *(const f4*)(hstart + base1 + q * 4);
#pragma unroll
            for (int i = 0; i < 4; ++i) h2[q * 4 + i] = (f2){ h0[i], h1[i] };
        }
    }

    f2 dbuf[2], ubuf[2];
#pragma unroll
    for (int j = 0; j < 2; ++j) { dbuf[j] = *(const f2*)(dp + j * C_DIM); ubuf[j] = *(const f2*)(up + j * us); }

    for (int jj = 0; jj < CLEN; jj += 2) {
        int nx = (jj + 2 < CLEN) ? jj + 2 : jj;
        f2 dn[2], un[2];
#pragma unroll
        for (int j = 0; j < 2; ++j) { dn[j] = *(const f2*)(dp + (nx + j) * C_DIM); un[j] = *(const f2*)(up + (nx + j) * us); }
#pragma unroll
        for (int j = 0; j < 2; ++j) {
            int li = chl * CLEN + jj + j;
            f2 dv = dbuf[j];
            f2 uv = ubuf[j];
            f2 du2 = dv * uv;
            const f4* Bl = Bsh + (size_t)li * 4;
            const f4* Cl = Csh + (size_t)li * 4;
            f2 ya = dsc * uv, yb = {0.f, 0.f}, yc = {0.f, 0.f}, yd = {0.f, 0.f};
#pragma unroll
            for (int q = 0; q < 4; ++q) {
                f4 Bq = Bl[q];
                f4 Cq = Cl[q];
                {
                    f2 m = dv * a2[q * 4 + 0];
                    f2 e = { fexp2(m.x), fexp2(m.y) };
                    h2[q * 4 + 0] = pkfma(h2[q * 4 + 0], e, du2 * (f2){Bq[0], Bq[0]});
                    ya = pkfma(h2[q * 4 + 0], (f2){Cq[0], Cq[0]}, ya);
                }
                {
                    f2 m = dv * a2[q * 4 + 1];
                    f2 e = { fexp2(m.x), fexp2(m.y) };
                    h2[q * 4 + 1] = pkfma(h2[q * 4 + 1], e, du2 * (f2){Bq[1], Bq[1]});
                    yb = pkfma(h2[q * 4 + 1], (f2){Cq[1], Cq[1]}, yb);
                }
                {
                    f2 m = dv * a2[q * 4 + 2];
                    f2 e = { fexp2(m.x), fexp2(m.y) };
                    h2[q * 4 + 2] = pkfma(h2[q * 4 + 2], e, du2 * (f2){Bq[2], Bq[2]});
                    yc = pkfma(h2[q * 4 + 2], (f2){Cq[2], Cq[2]}, yc);
                }
                {
                    f2 m = dv * a2[q * 4 + 3];
                    f2 e = { fexp2(m.x), fexp2(m.y) };
                    h2[q * 4 + 3] = pkfma(h2[q * 4 + 3], e, du2 * (f2){Bq[3], Bq[3]});
                    yd = pkfma(h2[q * 4 + 3], (f2){Cq[3], Cq[3]}, yd);
                }
            }
            f2 yv = (ya + yb) + (yc + yd);
            *(f2*)(yp + (jj + j) * C_DIM) = yv;
        }
#pragma unroll
        for (int j = 0; j < 2; ++j) { dbuf[j] = dn[j]; ubuf[j] = un[j]; }
    }
}

// ---------------- K3: fold (un-scan) + LayerNorm, fused ([l][c] input) ----------------
__global__ __launch_bounds__(256) void k3_out(
    const float* __restrict__ yssT, const float* __restrict__ nw,
    const float* __restrict__ nb, float* __restrict__ out)
{
    __shared__ float tA[32][97];
    __shared__ float tB[32][97];
    __shared__ float ps[4][8][32];
    __shared__ float stat[4][32];

    int blk = blockIdx.x;
    int h = blk & 31;
    int bs = blk >> 5;
    int so = bs & 1;
    int b = bs >> 1;
    int tid = (int)threadIdx.x;

    auto Y = [&](int g) { return yssT + (size_t)(b * 12 + g) * L_LEN * C_DIM; };
    const float* Y0 = Y(so);
    const float* Y0r = Y(6 + so);
    const float* Y1 = Y(3 + so);
    const float* Y1r = Y(9 + so);

#pragma unroll 2
    for (int it = 0; it < 24; ++it) {
        int idx = tid + it * 256;
        int c = idx % 96, rest = idx / 96;
        int w = rest >> 1, par = rest & 1;
        int a0 = h * 64 + rest;
        int a1 = w * 64 + 2 * h + par;
        float v = Y0[(size_t)a0 * C_DIM + c] + Y0r[(size_t)(2047 - a0) * C_DIM + c]
                + Y1[(size_t)a1 * C_DIM + c] + Y1r[(size_t)(2047 - a1) * C_DIM + c];
        if (par) tA[w][c] = v; else tB[w][c] = v;
    }
    __syncthreads();

    int w = tid & 31, cg = tid >> 5;
    float sA = 0, qA = 0, sB = 0, qB = 0;
#pragma unroll
    for (int j = 0; j < 12; ++j) {
        float yv = tA[w][cg * 12 + j], dv = tB[w][cg * 12 + j];
        sA += yv; qA += yv * yv; sB += dv; qB += dv * dv;
    }
    ps[0][cg][w] = sA; ps[1][cg][w] = qA; ps[2][cg][w] = sB; ps[3][cg][w] = qB;
    __syncthreads();
    if (tid < 32) {
        int ww = tid;
        float t0 = 0, t1 = 0, t2 = 0, t3 = 0;
#pragma unroll
        for (int q = 0; q < 8; ++q) {
            t0 += ps[0][q][ww]; t1 += ps[1][q][ww];
            t2 += ps[2][q][ww]; t3 += ps[3][q][ww];
        }
        float muA = t0 * (1.f / 96.f), eqA = t1 * (1.f / 96.f);
        float muB = t2 * (1.f / 96.f), eqB = t3 * (1.f / 96.f);
        stat[0][ww] = muA; stat[1][ww] = rsqrtf(eqA - muA * muA + 1e-5f);
        stat[2][ww] = muB; stat[3][ww] = rsqrtf(eqB - muB * muB + 1e-5f);
    }
    __syncthreads();
    size_t obase = (size_t)blk * 3072;
    for (int e = tid; e < 3072; e += 256) {
        int ww = e / 96, c = e % 96;
        float wc = nw[c], bc = nb[c];
        out[obase + e] = (tA[ww][c] - stat[0][ww]) * stat[1][ww] * wc + bc;
        out[2 * 786432 + obase + e] = (tB[ww][c] - stat[2][ww]) * stat[3][ww] * wc + bc;
    }
    __syncthreads();

    const float* Y2 = Y(2);
    const float* Y2r = Y(8);
    const float* Y3 = Y(5);
    const float* Y3r = Y(11);
#pragma unroll 2
    for (int it = 0; it < 12; ++it) {
        int idx = tid + it * 256;
        int c = idx % 96, w2 = idx / 96;
        int a0 = h * 64 + 2 * w2 + so;
        int a1 = w2 * 64 + 2 * h + so;
        float v = Y2[(size_t)a0 * C_DIM + c] + Y2r[(size_t)(2047 - a0) * C_DIM + c]
                + Y3[(size_t)a1 * C_DIM + c] + Y3r[(size_t)(2047 - a1) * C_DIM + c];
        tA[w2][c] = v;
    }
    __syncthreads();
    float sC = 0, qC = 0;
#pragma unroll
    for (int j = 0; j < 12; ++j) {
        float v = tA[w][cg * 12 + j];
        sC += v; qC += v * v;
    }
    ps[0][cg][w] = sC; ps[1][cg][w] = qC;
    __syncthreads();
    if (tid < 32) {
        int ww = tid;
        float t0 = 0, t1 = 0;
#pragma unroll
        for (int q = 0; q < 8; ++q) { t0 += ps[0][q][ww]; t1 += ps[1][q][ww]; }
        float mu = t0 * (1.f / 96.f), eq = t1 * (1.f / 96.f);
        stat[0][ww] = mu; stat[1][ww] = rsqrtf(eq - mu * mu + 1e-5f);
    }
    __syncthreads();
    for (int e = tid; e < 3072; e += 256) {
        int ww = e / 96, c = e % 96;
        out[786432 + obase + e] = (tA[ww][c] - stat[0][ww]) * stat[1][ww] * nw[c] + nb[c];
    }
}

extern "C" void kernel_launch(void* const* d_in, const int* in_sizes, int n_in,
                              void* d_out, int out_size, void* d_ws, size_t ws_size,
                              hipStream_t stream)
{
    const float* x = (const float*)d_in[0];
    const float* xpw = (const float*)d_in[1];
    const float* dtw = (const float*)d_in[2];
    const float* dtb = (const float*)d_in[3];
    const float* A_logs = (const float*)d_in[4];
    const float* Ds = (const float*)d_in[5];
    const float* nw = (const float*)d_in[6];
    const float* nb = (const float*)d_in[7];
    float* out = (float*)d_out;

    float* ws = (float*)d_ws;
    float* deltaT = ws;                // SZ_DELTA
    float* dts8 = deltaT + SZ_DELTA;   // SZ_DTS8
    float* Bsw = dts8 + SZ_DTS8;       // SZ_BC
    float* Csw = Bsw + SZ_BC;          // SZ_BC
    float* u6T = Csw + SZ_BC;          // SZ_U6
    float* yssT = u6T + SZ_U6;         // SZ_Y (xT+wpad aliased: dead before scanC)
    float* xT = yssT;                  // SZ_X (alias)
    float* wpad = yssT + SZ_X;         // SZ_WPAD (alias)
    float* hend = yssT + SZ_Y;         // SZ_H (becomes hstart in place)
    float* Sbuf = hend + SZ_H;         // SZ_S

    k0_xT<<<dim3(768), dim3(256), 0, stream>>>(x, xT);
    k0b_padw<<<dim3(180), dim3(256), 0, stream>>>(xpw, wpad);
    k1_proj<<<dim3(24 * 32), dim3(256), 0, stream>>>(x, xT, wpad, dts8, Bsw, Csw, u6T);
    k1b_delta<<<dim3(48 * 32), dim3(256), 0, stream>>>(dts8, dtw, dtb, deltaT);
    k2_scanA<<<dim3(48 * 32), dim3(96), 0, stream>>>(deltaT, Bsw, u6T, A_logs, hend, Sbuf);
    k2_fix<<<dim3(288), dim3(256), 0, stream>>>(Sbuf, A_logs, hend);
    k2_scanC<<<dim3(48 * 32), dim3(96), 0, stream>>>(deltaT, Bsw, Csw, u6T, A_logs, Ds, hend, yssT);
    k3_out<<<dim3(256), dim3(256), 0, stream>>>(yssT, nw, nb, out);
}

// Round 17
// 158.209 us; speedup vs baseline: 1.1031x; 1.1031x over previous
//
#include <hip/hip_runtime.h>
#include <math.h>

typedef float f4 __attribute__((ext_vector_type(4)));
typedef float f2 __attribute__((ext_vector_type(2)));

#define L_LEN 2048
#define C_DIM 96
#define N_DIM 16
#define R_DIM 6
#define G_DIM 12
#define B_DIM 4
#define NCHUNK 64
#define CLEN 32
#define BGC (B_DIM * G_DIM * C_DIM) // 4608

// workspace layout (floats)
#define SZ_DELTA (B_DIM * G_DIM * L_LEN * C_DIM) // 9437184
#define SZ_BC (B_DIM * G_DIM * N_DIM * L_LEN)    // 1572864
#define SZ_U6 (B_DIM * 6 * C_DIM * L_LEN)        // 4718592
#define SZ_Y (B_DIM * G_DIM * C_DIM * L_LEN)     // 9437184
#define SZ_H (BGC * NCHUNK * N_DIM)              // 4718592
#define SZ_S (BGC * NCHUNK)                      // 294912
#define SZ_X (B_DIM * 2 * C_DIM * 1024)          // 786432
#define SZ_WPAD (G_DIM * 40 * C_DIM)             // 46080

__device__ __forceinline__ float fexp2(float x) { return __builtin_amdgcn_exp2f(x); }

__device__ __forceinline__ float softplus_f(float x)
{
    float sp = __logf(1.f + __expf(x));
    return (x > 20.f) ? x : sp;
}

// ---------------- K0: transpose x (H<->W) for odd-k coalescing ----------------
__global__ __launch_bounds__(256) void k0_xT(
    const float* __restrict__ x, float* __restrict__ xT)
{
    __shared__ float t[32][33];
    int img = blockIdx.x;
    const float* src = x + (size_t)img * 1024;
    float* dst = xT + (size_t)img * 1024;
    int tx = threadIdx.x & 31, ty = threadIdx.x >> 5;
#pragma unroll
    for (int r = 0; r < 32; r += 8) t[ty + r][tx] = src[(ty + r) * 32 + tx];
    __syncthreads();
#pragma unroll
    for (int r = 0; r < 32; r += 8) dst[(ty + r) * 32 + tx] = t[tx][ty + r];
}

// ---------------- K0b: zero-pad x_proj_weight rows 38->40 ----------------
__global__ __launch_bounds__(256) void k0b_padw(
    const float* __restrict__ xpw, float* __restrict__ wpad)
{
    int i = blockIdx.x * 256 + (int)threadIdx.x;
    if (i >= G_DIM * 40 * C_DIM) return;
    int g = i / (40 * C_DIM);
    int rem = i - g * 40 * C_DIM;
    int p = rem / C_DIM, c = rem - (rem / C_DIM) * C_DIM;
    wpad[i] = (p < 38) ? xpw[((size_t)g * 38 + p) * C_DIM + c] : 0.f;
}

// ---------------- K1: paired cross-scan gather + projections (32-l tiles) ----------------
// grid 1536 = 24 bks x 64 ltiles; block 256 = 32 l x 8 p-groups of 5.
__global__ __launch_bounds__(256) void k1_proj(
    const float* __restrict__ x, const float* __restrict__ xT,
    const float* __restrict__ wpad, const float* __restrict__ dtw,
    const float* __restrict__ dtb,
    float* __restrict__ deltaT, float* __restrict__ Bsw,
    float* __restrict__ Csw, float* __restrict__ u6T)
{
    __shared__ float Vsh[C_DIM * 36];  // [c][36] over 32 l (f4-aligned stride)
    __shared__ float Psh[40][33];

    int blk = blockIdx.x;      // bks*64 + ltile
    int ltile = blk & 63;
    int bks = blk >> 6;        // 0..23
    int s = bks % 3;
    int k = (bks / 3) & 1;
    int b = bks / 6;
    int g = k * 3 + s;
    int gh = g + 6;
    int l0 = ltile * 32;
    int l0h = (63 - ltile) * 32;
    int bg = b * G_DIM + g;
    int bgh = b * G_DIM + gh;
    int tid = (int)threadIdx.x;

    const float* xb = (k ? xT : x) + (size_t)b * 2 * C_DIM * 1024;

    // ---- stage V[c][ll]: 96c x 8 groups of 4 l = 768 f4 slots ----
#pragma unroll
    for (int j = 0; j < 3; ++j) {
        int e = tid + j * 256;       // < 768
        int c = e >> 3;
        int llq = (e & 7) * 4;
        int pp = (l0 + llq) >> 1;
        f2 x0 = *(const f2*)(xb + (size_t)c * 1024 + pp);
        f2 x1 = *(const f2*)(xb + (size_t)(C_DIM + c) * 1024 + pp);
        f4 v;
        if (s == 2)      { v[0] = x0.x; v[1] = x1.x; v[2] = x0.y; v[3] = x1.y; }
        else if (s == 1) { v[0] = x1.x - x0.x; v[1] = x1.x; v[2] = x1.y - x0.y; v[3] = x1.y; }
        else             { v[0] = x0.x - x1.x; v[1] = x0.x; v[2] = x0.y - x1.y; v[3] = x0.y; }
        *(f4*)(Vsh + c * 36 + llq) = v;
    }
    __syncthreads();

    // ---- u6T[b6g][l][c] (coalesced f4) ----
    {
        size_t ub = ((size_t)(b * 6 + g) * L_LEN + l0) * C_DIM;
#pragma unroll
        for (int j = 0; j < 3; ++j) {
            int e = tid + j * 256;   // < 768
            int lidx = e / 24;
            int c4 = (e - lidx * 24) * 4;
            f4 v = { Vsh[(c4 + 0) * 36 + lidx], Vsh[(c4 + 1) * 36 + lidx],
                     Vsh[(c4 + 2) * 36 + lidx], Vsh[(c4 + 3) * 36 + lidx] };
            *(f4*)(u6T + ub + (size_t)lidx * C_DIM + c4) = v;
        }
    }

    // ---- register GEMM for g and gh (5 p-rows/thread) ----
    int ll = tid & 31;
    int P0 = (tid >> 5) * 5;   // NOT readfirstlane: 32-thread groups are not wave-uniform
    const float* wp = wpad + (size_t)g * 3840 + (size_t)P0 * C_DIM;
    const float* wph = wpad + (size_t)gh * 3840 + (size_t)P0 * C_DIM;

    float acc[5], acch[5];
#pragma unroll
    for (int p = 0; p < 5; ++p) { acc[p] = 0.f; acch[p] = 0.f; }

    for (int cb = 0; cb < C_DIM; cb += 8) {
        float vc[8], vch[8];
#pragma unroll
        for (int i = 0; i < 8; ++i) {
            vc[i] = Vsh[(cb + i) * 36 + ll];
            vch[i] = Vsh[(cb + i) * 36 + 31 - ll];
        }
#pragma unroll
        for (int p = 0; p < 5; ++p) {
#pragma unroll
            for (int q = 0; q < 2; ++q) {
                f4 w = *(const f4*)(wp + p * C_DIM + cb + q * 4);
                f4 wh = *(const f4*)(wph + p * C_DIM + cb + q * 4);
#pragma unroll
                for (int i = 0; i < 4; ++i) {
                    acc[p] = fmaf(w[i], vc[q * 4 + i], acc[p]);
                    acch[p] = fmaf(wh[i], vch[q * 4 + i], acch[p]);
                }
            }
        }
    }

    // ---- transpose via Psh, coalesced stores + delta epilogue (g then gh) ----
#pragma unroll
    for (int gg = 0; gg < 2; ++gg) {
        __syncthreads();
#pragma unroll
        for (int p = 0; p < 5; ++p) Psh[P0 + p][ll] = gg ? acch[p] : acc[p];
        __syncthreads();
        int lb = gg ? l0h : l0;
        int bgx = gg ? bgh : bg;
        int gx = gg ? gh : g;
        // B: threads 0..127, C: threads 128..255 (1 f4 store each)
        {
            int t2 = tid & 127;
            int q = t2 & 3, lx = t2 >> 2;
            int base = (tid < 128) ? 6 : 22;
            float* dst = (tid < 128) ? Bsw : Csw;
            f4 v = { Psh[base + q * 4 + 0][lx], Psh[base + q * 4 + 1][lx],
                     Psh[base + q * 4 + 2][lx], Psh[base + q * 4 + 3][lx] };
            *(f4*)(dst + ((size_t)bgx * L_LEN + lb + lx) * N_DIM + q * 4) = v;
        }
        // delta = softplus(bias + dts . wd), coalesced over c
        const float* wdg = dtw + (size_t)gx * C_DIM * R_DIM;
        const float* biasg = dtb + gx * C_DIM;
        size_t db = ((size_t)bgx * L_LEN + lb) * C_DIM;
#pragma unroll
        for (int it = 0; it < 12; ++it) {
            int e = tid + it * 256;
            int lidx = e / 96, c = e - (e / 96) * 96;
            float dsum = biasg[c];
#pragma unroll
            for (int r = 0; r < R_DIM; ++r) dsum = fmaf(Psh[r][lidx], wdg[c * R_DIM + r], dsum);
            deltaT[db + (size_t)lidx * C_DIM + c] = softplus_f(dsum);
        }
    }
}

// ---------------- K2: chunk-parallel scan (R12 version) ----------------
// Pass A: per chunk with h0=0, write h_end[16] and S = sum(d) per chunk.
__global__ __launch_bounds__(192) void k2_scanA(
    const float* __restrict__ deltaT, const float* __restrict__ Bsw,
    const float* __restrict__ u6T, const float* __restrict__ A_logs,
    float* __restrict__ hend, float* __restrict__ Sbuf)
{
    __shared__ f4 Bsh[256];     // 64 l x 16 n
    int blk = blockIdx.x;
    int chgrp = blk & 31;
    int bg = blk >> 5;
    int g = bg % G_DIM;
    int b = bg / G_DIM;
    int tid = (int)threadIdx.x;

    const f4* Bg = (const f4*)(Bsw + ((size_t)bg * L_LEN + chgrp * 64) * N_DIM);
    for (int i = tid; i < 256; i += 192) Bsh[i] = Bg[i];
    __syncthreads();

    int chl = tid / 96;
    int c = tid % 96;
    int ch = chgrp * 2 + chl;
    int bgc = bg * C_DIM + c;
    const bool rev = (g >= 6);
    int gu = rev ? (g - 6) : g;

    float a2[N_DIM];
    {
        const f4* Ap = (const f4*)(A_logs + ((size_t)g * C_DIM + c) * N_DIM);
        f4 Av[4] = { Ap[0], Ap[1], Ap[2], Ap[3] };
#pragma unroll
        for (int n = 0; n < N_DIM; ++n)
            a2[n] = -__expf(Av[n >> 2][n & 3]) * 1.44269504f;
    }

    const int LOFF = ch * CLEN;
    const float* dp = deltaT + ((size_t)bg * L_LEN + LOFF) * C_DIM + c;
    const float* up;
    int us;
    if (rev) { up = u6T + ((size_t)(b * 6 + gu) * L_LEN + (2047 - LOFF)) * C_DIM + c; us = -C_DIM; }
    else     { up = u6T + ((size_t)(b * 6 + gu) * L_LEN + LOFF) * C_DIM + c; us = C_DIM; }

    float h[N_DIM];
#pragma unroll
    for (int n = 0; n < N_DIM; ++n) h[n] = 0.f;
    float S = 0.f;

    float dbuf[4], ubuf[4];
#pragma unroll
    for (int j = 0; j < 4; ++j) { dbuf[j] = dp[j * C_DIM]; ubuf[j] = up[j * us]; }

    for (int jj = 0; jj < CLEN; jj += 4) {
        int nx = (jj + 4 < CLEN) ? jj + 4 : jj;
        float dn[4], un[4];
#pragma unroll
        for (int j = 0; j < 4; ++j) { dn[j] = dp[(nx + j) * C_DIM]; un[j] = up[(nx + j) * us]; }
#pragma unroll
        for (int j = 0; j < 4; ++j) {
            int li = chl * CLEN + jj + j;
            float d = dbuf[j];
            S += d;
            float du = d * ubuf[j];
            const f4* Bl = Bsh + (size_t)li * 4;
            f4 Bv[4] = { Bl[0], Bl[1], Bl[2], Bl[3] };
#pragma unroll
            for (int n = 0; n < N_DIM; ++n) {
                float e = fexp2(d * a2[n]);
                h[n] = fmaf(h[n], e, du * Bv[n >> 2][n & 3]);
            }
        }
#pragma unroll
        for (int j = 0; j < 4; ++j) { dbuf[j] = dn[j]; ubuf[j] = un[j]; }
    }
    float* hp = hend + ((size_t)bgc * NCHUNK + ch) * N_DIM;
#pragma unroll
    for (int q = 0; q < 4; ++q) {
        f4 hv = { h[q * 4], h[q * 4 + 1], h[q * 4 + 2], h[q * 4 + 3] };
        *(f4*)(hp + q * 4) = hv;
    }
    Sbuf[(size_t)bgc * NCHUNK + ch] = S;
}

// Pass B: compose chunk propagators; hend -> hstart IN PLACE (P recomputed from S).
__global__ __launch_bounds__(256) void k2_fix(
    const float* __restrict__ Sbuf, const float* __restrict__ A_logs, float* hh)
{
    int t = blockIdx.x * 256 + (int)threadIdx.x; // 73728
    int n = t & 15;
    int bgc = t >> 4;
    int c = bgc % C_DIM;
    int g = (bgc / C_DIM) % G_DIM;
    float a2 = -__expf(A_logs[((size_t)g * C_DIM + c) * N_DIM + n]) * 1.44269504f;
    const float* Sp = Sbuf + (size_t)bgc * NCHUNK;
    float h = 0.f;
    for (int ch = 0; ch < NCHUNK; ++ch) {
        size_t idx = ((size_t)bgc * NCHUNK + ch) * N_DIM + n;
        float he = hh[idx];
        float P = fexp2(a2 * Sp[ch]);
        hh[idx] = h;
        h = fmaf(h, P, he);
    }
}

// Pass C: exact recurrence from hstart, writes yT [bg][l][c] (+Ds*u folded).
__global__ __launch_bounds__(192) void k2_scanC(
    const float* __restrict__ deltaT, const float* __restrict__ Bsw,
    const float* __restrict__ Csw, const float* __restrict__ u6T,
    const float* __restrict__ A_logs, const float* __restrict__ Ds,
    const float* __restrict__ hstart, float* __restrict__ yssT)
{
    __shared__ f4 Bsh[256];
    __shared__ f4 Csh[256];
    int blk = blockIdx.x;
    int chgrp = blk & 31;
    int bg = blk >> 5;
    int g = bg % G_DIM;
    int b = bg / G_DIM;
    int tid = (int)threadIdx.x;

    const f4* Bg = (const f4*)(Bsw + ((size_t)bg * L_LEN + chgrp * 64) * N_DIM);
    const f4* Cg = (const f4*)(Csw + ((size_t)bg * L_LEN + chgrp * 64) * N_DIM);
    for (int i = tid; i < 256; i += 192) { Bsh[i] = Bg[i]; Csh[i] = Cg[i]; }
    __syncthreads();

    int chl = tid / 96;
    int c = tid % 96;
    int ch = chgrp * 2 + chl;
    int bgc = bg * C_DIM + c;
    const bool rev = (g >= 6);
    int gu = rev ? (g - 6) : g;

    float a2[N_DIM];
    {
        const f4* Ap = (const f4*)(A_logs + ((size_t)g * C_DIM + c) * N_DIM);
        f4 Av[4] = { Ap[0], Ap[1], Ap[2], Ap[3] };
#pragma unroll
        for (int n = 0; n < N_DIM; ++n)
            a2[n] = -__expf(Av[n >> 2][n & 3]) * 1.44269504f;
    }
    float dsc = Ds[g * C_DIM + c];

    const int LOFF = ch * CLEN;
    const float* dp = deltaT + ((size_t)bg * L_LEN + LOFF) * C_DIM + c;
    const float* up;
    int us;
    if (rev) { up = u6T + ((size_t)(b * 6 + gu) * L_LEN + (2047 - LOFF)) * C_DIM + c; us = -C_DIM; }
    else     { up = u6T + ((size_t)(b * 6 + gu) * L_LEN + LOFF) * C_DIM + c; us = C_DIM; }
    float* yp = yssT + ((size_t)bg * L_LEN + LOFF) * C_DIM + c;

    float h[N_DIM];
    {
        const f4* Hp = (const f4*)(hstart + ((size_t)bgc * NCHUNK + ch) * N_DIM);
        f4 Hv[4] = { Hp[0], Hp[1], Hp[2], Hp[3] };
#pragma unroll
        for (int n = 0; n < N_DIM; ++n) h[n] = Hv[n >> 2][n & 3];
    }

    float dbuf[4], ubuf[4];
#pragma unroll
    for (int j = 0; j < 4; ++j) { dbuf[j] = dp[j * C_DIM]; ubuf[j] = up[j * us]; }

    for (int jj = 0; jj < CLEN; jj += 4) {
        int nx = (jj + 4 < CLEN) ? jj + 4 : jj;
        float dn[4], un[4];
#pragma unroll
        for (int j = 0; j < 4; ++j) { dn[j] = dp[(nx + j) * C_DIM]; un[j] = up[(nx + j) * us]; }
#pragma unroll
        for (int j = 0; j < 4; ++j) {
            int li = chl * CLEN + jj + j;
            float d = dbuf[j];
            float uu = ubuf[j];
            float du = d * uu;
            const f4* Bl = Bsh + (size_t)li * 4;
            const f4* Cl = Csh + (size_t)li * 4;
            f4 Bv[4] = { Bl[0], Bl[1], Bl[2], Bl[3] };
            f4 Cv[4] = { Cl[0], Cl[1], Cl[2], Cl[3] };
            float y0 = dsc * uu, y1 = 0.f, y2 = 0.f, y3 = 0.f;
#pragma unroll
            for (int q = 0; q < 4; ++q) {
                float e0 = fexp2(d * a2[q * 4 + 0]);
                float e1 = fexp2(d * a2[q * 4 + 1]);
                float e2 = fexp2(d * a2[q * 4 + 2]);
                float e3 = fexp2(d * a2[q * 4 + 3]);
                h[q * 4 + 0] = fmaf(h[q * 4 + 0], e0, du * Bv[q][0]);
                h[q * 4 + 1] = fmaf(h[q * 4 + 1], e1, du * Bv[q][1]);
                h[q * 4 + 2] = fmaf(h[q * 4 + 2], e2, du * Bv[q][2]);
                h[q * 4 + 3] = fmaf(h[q * 4 + 3], e3, du * Bv[q][3]);
                y0 = fmaf(h[q * 4 + 0], Cv[q][0], y0);
                y1 = fmaf(h[q * 4 + 1], Cv[q][1], y1);
                y2 = fmaf(h[q * 4 + 2], Cv[q][2], y2);
                y3 = fmaf(h[q * 4 + 3], Cv[q][3], y3);
            }
            yp[(jj + j) * C_DIM] = (y0 + y1) + (y2 + y3);
        }
#pragma unroll
        for (int j = 0; j < 4; ++j) { dbuf[j] = dn[j]; ubuf[j] = un[j]; }
    }
}

// ---------------- K3: fold (un-scan) + LayerNorm, fused ([l][c] input) ----------------
__global__ __launch_bounds__(256) void k3_out(
    const float* __restrict__ yssT, const float* __restrict__ nw,
    const float* __restrict__ nb, float* __restrict__ out)
{
    __shared__ float tA[32][97];
    __shared__ float tB[32][97];
    __shared__ float ps[4][8][32];
    __shared__ float stat[4][32];

    int blk = blockIdx.x;
    int h = blk & 31;
    int bs = blk >> 5;
    int so = bs & 1;
    int b = bs >> 1;
    int tid = (int)threadIdx.x;

    auto Y = [&](int g) { return yssT + (size_t)(b * 12 + g) * L_LEN * C_DIM; };
    const float* Y0 = Y(so);
    const float* Y0r = Y(6 + so);
    const float* Y1 = Y(3 + so);
    const float* Y1r = Y(9 + so);

#pragma unroll 2
    for (int it = 0; it < 24; ++it) {
        int idx = tid + it * 256;
        int c = idx % 96, rest = idx / 96;
        int w = rest >> 1, par = rest & 1;
        int a0 = h * 64 + rest;
        int a1 = w * 64 + 2 * h + par;
        float v = Y0[(size_t)a0 * C_DIM + c] + Y0r[(size_t)(2047 - a0) * C_DIM + c]
                + Y1[(size_t)a1 * C_DIM + c] + Y1r[(size_t)(2047 - a1) * C_DIM + c];
        if (par) tA[w][c] = v; else tB[w][c] = v;
    }
    __syncthreads();

    int w = tid & 31, cg = tid >> 5;
    float sA = 0, qA = 0, sB = 0, qB = 0;
#pragma unroll
    for (int j = 0; j < 12; ++j) {
        float yv = tA[w][cg * 12 + j], dv = tB[w][cg * 12 + j];
        sA += yv; qA += yv * yv; sB += dv; qB += dv * dv;
    }
    ps[0][cg][w] = sA; ps[1][cg][w] = qA; ps[2][cg][w] = sB; ps[3][cg][w] = qB;
    __syncthreads();
    if (tid < 32) {
        int ww = tid;
        float t0 = 0, t1 = 0, t2 = 0, t3 = 0;
#pragma unroll
        for (int q = 0; q < 8; ++q) {
            t0 += ps[0][q][ww]; t1 += ps[1][q][ww];
            t2 += ps[2][q][ww]; t3 += ps[3][q][ww];
        }
        float muA = t0 * (1.f / 96.f), eqA = t1 * (1.f / 96.f);
        float muB = t2 * (1.f / 96.f), eqB = t3 * (1.f / 96.f);
        stat[0][ww] = muA; stat[1][ww] = rsqrtf(eqA - muA * muA + 1e-5f);
        stat[2][ww] = muB; stat[3][ww] = rsqrtf(eqB - muB * muB + 1e-5f);
    }
    __syncthreads();
    size_t obase = (size_t)blk * 3072;
    for (int e = tid; e < 3072; e += 256) {
        int ww = e / 96, c = e % 96;
        float wc = nw[c], bc = nb[c];
        out[obase + e] = (tA[ww][c] - stat[0][ww]) * stat[1][ww] * wc + bc;
        out[2 * 786432 + obase + e] = (tB[ww][c] - stat[2][ww]) * stat[3][ww] * wc + bc;
    }
    __syncthreads();

    const float* Y2 = Y(2);
    const float* Y2r = Y(8);
    const float* Y3 = Y(5);
    const float* Y3r = Y(11);
#pragma unroll 2
    for (int it = 0; it < 12; ++it) {
        int idx = tid + it * 256;
        int c = idx % 96, w2 = idx / 96;
        int a0 = h * 64 + 2 * w2 + so;
        int a1 = w2 * 64 + 2 * h + so;
        float v = Y2[(size_t)a0 * C_DIM + c] + Y2r[(size_t)(2047 - a0) * C_DIM + c]
                + Y3[(size_t)a1 * C_DIM + c] + Y3r[(size_t)(2047 - a1) * C_DIM + c];
        tA[w2][c] = v;
    }
    __syncthreads();
    float sC = 0, qC = 0;
#pragma unroll
    for (int j = 0; j < 12; ++j) {
        float v = tA[w][cg * 12 + j];
        sC += v; qC += v * v;
    }
    ps[0][cg][w] = sC; ps[1][cg][w] = qC;
    __syncthreads();
    if (tid < 32) {
        int ww = tid;
        float t0 = 0, t1 = 0;
#pragma unroll
        for (int q = 0; q < 8; ++q) { t0 += ps[0][q][ww]; t1 += ps[1][q][ww]; }
        float mu = t0 * (1.f / 96.f), eq = t1 * (1.f / 96.f);
        stat[0][ww] = mu; stat[1][ww] = rsqrtf(eq - mu * mu + 1e-5f);
    }
    __syncthreads();
    for (int e = tid; e < 3072; e += 256) {
        int ww = e / 96, c = e % 96;
        out[786432 + obase + e] = (tA[ww][c] - stat[0][ww]) * stat[1][ww] * nw[c] + nb[c];
    }
}

extern "C" void kernel_launch(void* const* d_in, const int* in_sizes, int n_in,
                              void* d_out, int out_size, void* d_ws, size_t ws_size,
                              hipStream_t stream)
{
    const float* x = (const float*)d_in[0];
    const float* xpw = (const float*)d_in[1];
    const float* dtw = (const float*)d_in[2];
    const float* dtb = (const float*)d_in[3];
    const float* A_logs = (const float*)d_in[4];
    const float* Ds = (const float*)d_in[5];
    const float* nw = (const float*)d_in[6];
    const float* nb = (const float*)d_in[7];
    float* out = (float*)d_out;

    float* ws = (float*)d_ws;
    float* deltaT = ws;                // SZ_DELTA
    float* Bsw = deltaT + SZ_DELTA;    // SZ_BC
    float* Csw = Bsw + SZ_BC;          // SZ_BC
    float* u6T = Csw + SZ_BC;          // SZ_U6
    float* yssT = u6T + SZ_U6;         // SZ_Y (xT+wpad aliased: dead before scanC)
    float* xT = yssT;                  // SZ_X (alias)
    float* wpad = yssT + SZ_X;         // SZ_WPAD (alias)
    float* hend = yssT + SZ_Y;         // SZ_H (becomes hstart in place)
    float* Sbuf = hend + SZ_H;         // SZ_S

    k0_xT<<<dim3(768), dim3(256), 0, stream>>>(x, xT);
    k0b_padw<<<dim3(180), dim3(256), 0, stream>>>(xpw, wpad);
    k1_proj<<<dim3(24 * 64), dim3(256), 0, stream>>>(x, xT, wpad, dtw, dtb, deltaT, Bsw, Csw, u6T);
    k2_scanA<<<dim3(48 * 32), dim3(192), 0, stream>>>(deltaT, Bsw, u6T, A_logs, hend, Sbuf);
    k2_fix<<<dim3(288), dim3(256), 0, stream>>>(Sbuf, A_logs, hend);
    k2_scanC<<<dim3(48 * 32), dim3(192), 0, stream>>>(deltaT, Bsw, Csw, u6T, A_logs, Ds, hend, yssT);
    k3_out<<<dim3(256), dim3(256), 0, stream>>>(yssT, nw, nb, out);
}

// Round 18
// 133.209 us; speedup vs baseline: 1.3101x; 1.1877x over previous
//
#include <hip/hip_runtime.h>
#include <math.h>

typedef float f4 __attribute__((ext_vector_type(4)));
typedef float f2 __attribute__((ext_vector_type(2)));

#define L_LEN 2048
#define C_DIM 96
#define N_DIM 16
#define R_DIM 6
#define G_DIM 12
#define B_DIM 4
#define NCHUNK 64
#define CLEN 32
#define BGC (B_DIM * G_DIM * C_DIM) // 4608

// workspace layout (floats)
#define SZ_DELTA (B_DIM * G_DIM * L_LEN * C_DIM) // 9437184
#define SZ_BC (B_DIM * G_DIM * N_DIM * L_LEN)    // 1572864
#define SZ_U6 (B_DIM * 6 * C_DIM * L_LEN)        // 4718592
#define SZ_Y (B_DIM * G_DIM * C_DIM * L_LEN)     // 9437184
#define SZ_H (BGC * NCHUNK * N_DIM)              // 4718592
#define SZ_S (BGC * NCHUNK)                      // 294912
#define SZ_X (B_DIM * 2 * C_DIM * 1024)          // 786432
#define SZ_WPAD (G_DIM * 40 * C_DIM)             // 46080

__device__ __forceinline__ float fexp2(float x) { return __builtin_amdgcn_exp2f(x); }

__device__ __forceinline__ float softplus_f(float x)
{
    float sp = __logf(1.f + __expf(x));
    return (x > 20.f) ? x : sp;
}

// ---------------- K0: transpose x (H<->W) for odd-k coalescing ----------------
__global__ __launch_bounds__(256) void k0_xT(
    const float* __restrict__ x, float* __restrict__ xT)
{
    __shared__ float t[32][33];
    int img = blockIdx.x;
    const float* src = x + (size_t)img * 1024;
    float* dst = xT + (size_t)img * 1024;
    int tx = threadIdx.x & 31, ty = threadIdx.x >> 5;
#pragma unroll
    for (int r = 0; r < 32; r += 8) t[ty + r][tx] = src[(ty + r) * 32 + tx];
    __syncthreads();
#pragma unroll
    for (int r = 0; r < 32; r += 8) dst[(ty + r) * 32 + tx] = t[tx][ty + r];
}

// ---------------- K0b: zero-pad x_proj_weight rows 38->40 ----------------
__global__ __launch_bounds__(256) void k0b_padw(
    const float* __restrict__ xpw, float* __restrict__ wpad)
{
    int i = blockIdx.x * 256 + (int)threadIdx.x;
    if (i >= G_DIM * 40 * C_DIM) return;
    int g = i / (40 * C_DIM);
    int rem = i - g * 40 * C_DIM;
    int p = rem / C_DIM, c = rem - (rem / C_DIM) * C_DIM;
    wpad[i] = (p < 38) ? xpw[((size_t)g * 38 + p) * C_DIM + c] : 0.f;
}

// ---------------- K1: cross-scan gather + projection, ONE g per block ----------------
// grid 1536 = 48 (b,g) x 32 ltiles; block 256 = 64 l x 4 p-groups of 10 (wave-uniform).
__global__ __launch_bounds__(256) void k1_proj(
    const float* __restrict__ x, const float* __restrict__ xT,
    const float* __restrict__ wpad, const float* __restrict__ dtw,
    const float* __restrict__ dtb,
    float* __restrict__ deltaT, float* __restrict__ Bsw,
    float* __restrict__ Csw, float* __restrict__ u6T)
{
    __shared__ float Vsh[C_DIM * 68];
    __shared__ float Psh[40][65];

    int blk = blockIdx.x;        // bks*32 + ltile
    int ltile = blk & 31;
    int bks = blk >> 5;          // 0..47 = b*12+g
    int g = bks % G_DIM;
    int b = bks / G_DIM;
    const bool rev = (g >= 6);
    int gu = rev ? (g - 6) : g;
    int k = gu / 3, s = gu % 3;
    int l0 = ltile * 64;
    int bg = b * G_DIM + g;
    int tid = (int)threadIdx.x;

    const float* xb = (k ? xT : x) + (size_t)b * 2 * C_DIM * 1024;

    // ---- stage V[c][ll] in OUTPUT-l space (reversal folded into pp + shuffle) ----
#pragma unroll
    for (int j = 0; j < 6; ++j) {
        int e = tid + j * 256;       // < 1536
        int c = e >> 4;
        int llq = (e & 15) * 4;
        int pp = rev ? (1022 - ((l0 + llq) >> 1)) : ((l0 + llq) >> 1);
        f2 x0 = *(const f2*)(xb + (size_t)c * 1024 + pp);
        f2 x1 = *(const f2*)(xb + (size_t)(C_DIM + c) * 1024 + pp);
        f4 v;
        if (!rev) {
            if (s == 2)      { v[0] = x0.x; v[1] = x1.x; v[2] = x0.y; v[3] = x1.y; }
            else if (s == 1) { v[0] = x1.x - x0.x; v[1] = x1.x; v[2] = x1.y - x0.y; v[3] = x1.y; }
            else             { v[0] = x0.x - x1.x; v[1] = x0.x; v[2] = x0.y - x1.y; v[3] = x0.y; }
        } else {
            if (s == 2)      { v[0] = x1.y; v[1] = x0.y; v[2] = x1.x; v[3] = x0.x; }
            else if (s == 1) { v[0] = x1.y; v[1] = x1.y - x0.y; v[2] = x1.x; v[3] = x1.x - x0.x; }
            else             { v[0] = x0.y; v[1] = x0.y - x1.y; v[2] = x0.x; v[3] = x0.x - x1.x; }
        }
        *(f4*)(Vsh + c * 68 + llq) = v;
    }
    __syncthreads();

    // ---- u6T[b6g][l][c] (g<6 only; coalesced f4) ----
    if (!rev) {
        size_t ub = ((size_t)(b * 6 + g) * L_LEN + l0) * C_DIM;
#pragma unroll
        for (int j = 0; j < 6; ++j) {
            int e = tid + j * 256;
            int lidx = e / 24;
            int c4 = (e - lidx * 24) * 4;
            f4 v = { Vsh[(c4 + 0) * 68 + lidx], Vsh[(c4 + 1) * 68 + lidx],
                     Vsh[(c4 + 2) * 68 + lidx], Vsh[(c4 + 3) * 68 + lidx] };
            *(f4*)(u6T + ub + (size_t)lidx * C_DIM + c4) = v;
        }
    }

    // ---- register GEMM (10 p-rows/thread, wave-uniform weights) ----
    int ll = tid & 63;
    int P0 = __builtin_amdgcn_readfirstlane((tid >> 6) * 10);
    const float* wp = wpad + (size_t)g * 3840 + (size_t)P0 * C_DIM;

    float acc[10];
#pragma unroll
    for (int p = 0; p < 10; ++p) acc[p] = 0.f;

    for (int cb = 0; cb < C_DIM; cb += 8) {
        float vc[8];
#pragma unroll
        for (int i = 0; i < 8; ++i) vc[i] = Vsh[(cb + i) * 68 + ll];
#pragma unroll
        for (int p = 0; p < 10; ++p) {
#pragma unroll
            for (int q = 0; q < 2; ++q) {
                f4 w = *(const f4*)(wp + p * C_DIM + cb + q * 4);
#pragma unroll
                for (int i = 0; i < 4; ++i)
                    acc[p] = fmaf(w[i], vc[q * 4 + i], acc[p]);
            }
        }
    }

    // ---- transpose via Psh, coalesced B/C stores + delta epilogue ----
    __syncthreads();
#pragma unroll
    for (int p = 0; p < 10; ++p) Psh[P0 + p][ll] = acc[p];
    __syncthreads();
    {
        int q = tid & 3, lx = tid >> 2;
        f4 bv = { Psh[6 + q * 4 + 0][lx], Psh[6 + q * 4 + 1][lx],
                  Psh[6 + q * 4 + 2][lx], Psh[6 + q * 4 + 3][lx] };
        *(f4*)(Bsw + ((size_t)bg * L_LEN + l0 + lx) * N_DIM + q * 4) = bv;
        f4 cv = { Psh[22 + q * 4 + 0][lx], Psh[22 + q * 4 + 1][lx],
                  Psh[22 + q * 4 + 2][lx], Psh[22 + q * 4 + 3][lx] };
        *(f4*)(Csw + ((size_t)bg * L_LEN + l0 + lx) * N_DIM + q * 4) = cv;
    }
    const float* wdg = dtw + (size_t)g * C_DIM * R_DIM;
    const float* biasg = dtb + g * C_DIM;
    size_t db = ((size_t)bg * L_LEN + l0) * C_DIM;
#pragma unroll
    for (int it = 0; it < 24; ++it) {
        int e = tid + it * 256;
        int lidx = e / 96, c = e - (e / 96) * 96;
        float dsum = biasg[c];
#pragma unroll
        for (int r = 0; r < R_DIM; ++r) dsum = fmaf(Psh[r][lidx], wdg[c * R_DIM + r], dsum);
        deltaT[db + (size_t)lidx * C_DIM + c] = softplus_f(dsum);
    }
}

// ---------------- K2: chunk-parallel scan (R12 version) ----------------
// Pass A: per chunk with h0=0, write h_end[16] and S = sum(d) per chunk.
__global__ __launch_bounds__(192) void k2_scanA(
    const float* __restrict__ deltaT, const float* __restrict__ Bsw,
    const float* __restrict__ u6T, const float* __restrict__ A_logs,
    float* __restrict__ hend, float* __restrict__ Sbuf)
{
    __shared__ f4 Bsh[256];     // 64 l x 16 n
    int blk = blockIdx.x;
    int chgrp = blk & 31;
    int bg = blk >> 5;
    int g = bg % G_DIM;
    int b = bg / G_DIM;
    int tid = (int)threadIdx.x;

    const f4* Bg = (const f4*)(Bsw + ((size_t)bg * L_LEN + chgrp * 64) * N_DIM);
    for (int i = tid; i < 256; i += 192) Bsh[i] = Bg[i];
    __syncthreads();

    int chl = tid / 96;
    int c = tid % 96;
    int ch = chgrp * 2 + chl;
    int bgc = bg * C_DIM + c;
    const bool rev = (g >= 6);
    int gu = rev ? (g - 6) : g;

    float a2[N_DIM];
    {
        const f4* Ap = (const f4*)(A_logs + ((size_t)g * C_DIM + c) * N_DIM);
        f4 Av[4] = { Ap[0], Ap[1], Ap[2], Ap[3] };
#pragma unroll
        for (int n = 0; n < N_DIM; ++n)
            a2[n] = -__expf(Av[n >> 2][n & 3]) * 1.44269504f;
    }

    const int LOFF = ch * CLEN;
    const float* dp = deltaT + ((size_t)bg * L_LEN + LOFF) * C_DIM + c;
    const float* up;
    int us;
    if (rev) { up = u6T + ((size_t)(b * 6 + gu) * L_LEN + (2047 - LOFF)) * C_DIM + c; us = -C_DIM; }
    else     { up = u6T + ((size_t)(b * 6 + gu) * L_LEN + LOFF) * C_DIM + c; us = C_DIM; }

    float h[N_DIM];
#pragma unroll
    for (int n = 0; n < N_DIM; ++n) h[n] = 0.f;
    float S = 0.f;

    float dbuf[4], ubuf[4];
#pragma unroll
    for (int j = 0; j < 4; ++j) { dbuf[j] = dp[j * C_DIM]; ubuf[j] = up[j * us]; }

    for (int jj = 0; jj < CLEN; jj += 4) {
        int nx = (jj + 4 < CLEN) ? jj + 4 : jj;
        float dn[4], un[4];
#pragma unroll
        for (int j = 0; j < 4; ++j) { dn[j] = dp[(nx + j) * C_DIM]; un[j] = up[(nx + j) * us]; }
#pragma unroll
        for (int j = 0; j < 4; ++j) {
            int li = chl * CLEN + jj + j;
            float d = dbuf[j];
            S += d;
            float du = d * ubuf[j];
            const f4* Bl = Bsh + (size_t)li * 4;
            f4 Bv[4] = { Bl[0], Bl[1], Bl[2], Bl[3] };
#pragma unroll
            for (int n = 0; n < N_DIM; ++n) {
                float e = fexp2(d * a2[n]);
                h[n] = fmaf(h[n], e, du * Bv[n >> 2][n & 3]);
            }
        }
#pragma unroll
        for (int j = 0; j < 4; ++j) { dbuf[j] = dn[j]; ubuf[j] = un[j]; }
    }
    float* hp = hend + ((size_t)bgc * NCHUNK + ch) * N_DIM;
#pragma unroll
    for (int q = 0; q < 4; ++q) {
        f4 hv = { h[q * 4], h[q * 4 + 1], h[q * 4 + 2], h[q * 4 + 3] };
        *(f4*)(hp + q * 4) = hv;
    }
    Sbuf[(size_t)bgc * NCHUNK + ch] = S;
}

// Pass B: compose chunk propagators; hend -> hstart IN PLACE (P recomputed from S).
__global__ __launch_bounds__(256) void k2_fix(
    const float* __restrict__ Sbuf, const float* __restrict__ A_logs, float* hh)
{
    int t = blockIdx.x * 256 + (int)threadIdx.x; // 73728
    int n = t & 15;
    int bgc = t >> 4;
    int c = bgc % C_DIM;
    int g = (bgc / C_DIM) % G_DIM;
    float a2 = -__expf(A_logs[((size_t)g * C_DIM + c) * N_DIM + n]) * 1.44269504f;
    const float* Sp = Sbuf + (size_t)bgc * NCHUNK;
    float h = 0.f;
    for (int ch = 0; ch < NCHUNK; ++ch) {
        size_t idx = ((size_t)bgc * NCHUNK + ch) * N_DIM + n;
        float he = hh[idx];
        float P = fexp2(a2 * Sp[ch]);
        hh[idx] = h;
        h = fmaf(h, P, he);
    }
}

// Pass C: exact recurrence from hstart, writes yT [bg][l][c] (+Ds*u folded).
__global__ __launch_bounds__(192) void k2_scanC(
    const float* __restrict__ deltaT, const float* __restrict__ Bsw,
    const float* __restrict__ Csw, const float* __restrict__ u6T,
    const float* __restrict__ A_logs, const float* __restrict__ Ds,
    const float* __restrict__ hstart, float* __restrict__ yssT)
{
    __shared__ f4 Bsh[256];
    __shared__ f4 Csh[256];
    int blk = blockIdx.x;
    int chgrp = blk & 31;
    int bg = blk >> 5;
    int g = bg % G_DIM;
    int b = bg / G_DIM;
    int tid = (int)threadIdx.x;

    const f4* Bg = (const f4*)(Bsw + ((size_t)bg * L_LEN + chgrp * 64) * N_DIM);
    const f4* Cg = (const f4*)(Csw + ((size_t)bg * L_LEN + chgrp * 64) * N_DIM);
    for (int i = tid; i < 256; i += 192) { Bsh[i] = Bg[i]; Csh[i] = Cg[i]; }
    __syncthreads();

    int chl = tid / 96;
    int c = tid % 96;
    int ch = chgrp * 2 + chl;
    int bgc = bg * C_DIM + c;
    const bool rev = (g >= 6);
    int gu = rev ? (g - 6) : g;

    float a2[N_DIM];
    {
        const f4* Ap = (const f4*)(A_logs + ((size_t)g * C_DIM + c) * N_DIM);
        f4 Av[4] = { Ap[0], Ap[1], Ap[2], Ap[3] };
#pragma unroll
        for (int n = 0; n < N_DIM; ++n)
            a2[n] = -__expf(Av[n >> 2][n & 3]) * 1.44269504f;
    }
    float dsc = Ds[g * C_DIM + c];

    const int LOFF = ch * CLEN;
    const float* dp = deltaT + ((size_t)bg * L_LEN + LOFF) * C_DIM + c;
    const float* up;
    int us;
    if (rev) { up = u6T + ((size_t)(b * 6 + gu) * L_LEN + (2047 - LOFF)) * C_DIM + c; us = -C_DIM; }
    else     { up = u6T + ((size_t)(b * 6 + gu) * L_LEN + LOFF) * C_DIM + c; us = C_DIM; }
    float* yp = yssT + ((size_t)bg * L_LEN + LOFF) * C_DIM + c;

    float h[N_DIM];
    {
        const f4* Hp = (const f4*)(hstart + ((size_t)bgc * NCHUNK + ch) * N_DIM);
        f4 Hv[4] = { Hp[0], Hp[1], Hp[2], Hp[3] };
#pragma unroll
        for (int n = 0; n < N_DIM; ++n) h[n] = Hv[n >> 2][n & 3];
    }

    float dbuf[4], ubuf[4];
#pragma unroll
    for (int j = 0; j < 4; ++j) { dbuf[j] = dp[j * C_DIM]; ubuf[j] = up[j * us]; }

    for (int jj = 0; jj < CLEN; jj += 4) {
        int nx = (jj + 4 < CLEN) ? jj + 4 : jj;
        float dn[4], un[4];
#pragma unroll
        for (int j = 0; j < 4; ++j) { dn[j] = dp[(nx + j) * C_DIM]; un[j] = up[(nx + j) * us]; }
#pragma unroll
        for (int j = 0; j < 4; ++j) {
            int li = chl * CLEN + jj + j;
            float d = dbuf[j];
            float uu = ubuf[j];
            float du = d * uu;
            const f4* Bl = Bsh + (size_t)li * 4;
            const f4* Cl = Csh + (size_t)li * 4;
            f4 Bv[4] = { Bl[0], Bl[1], Bl[2], Bl[3] };
            f4 Cv[4] = { Cl[0], Cl[1], Cl[2], Cl[3] };
            float y0 = dsc * uu, y1 = 0.f, y2 = 0.f, y3 = 0.f;
#pragma unroll
            for (int q = 0; q < 4; ++q) {
                float e0 = fexp2(d * a2[q * 4 + 0]);
                float e1 = fexp2(d * a2[q * 4 + 1]);
                float e2 = fexp2(d * a2[q * 4 + 2]);
                float e3 = fexp2(d * a2[q * 4 + 3]);
                h[q * 4 + 0] = fmaf(h[q * 4 + 0], e0, du * Bv[q][0]);
                h[q * 4 + 1] = fmaf(h[q * 4 + 1], e1, du * Bv[q][1]);
                h[q * 4 + 2] = fmaf(h[q * 4 + 2], e2, du * Bv[q][2]);
                h[q * 4 + 3] = fmaf(h[q * 4 + 3], e3, du * Bv[q][3]);
                y0 = fmaf(h[q * 4 + 0], Cv[q][0], y0);
                y1 = fmaf(h[q * 4 + 1], Cv[q][1], y1);
                y2 = fmaf(h[q * 4 + 2], Cv[q][2], y2);
                y3 = fmaf(h[q * 4 + 3], Cv[q][3], y3);
            }
            yp[(jj + j) * C_DIM] = (y0 + y1) + (y2 + y3);
        }
#pragma unroll
        for (int j = 0; j < 4; ++j) { dbuf[j] = dn[j]; ubuf[j] = un[j]; }
    }
}

// ---------------- K3: fold (un-scan) + LayerNorm, fused ([l][c] input) ----------------
__global__ __launch_bounds__(256) void k3_out(
    const float* __restrict__ yssT, const float* __restrict__ nw,
    const float* __restrict__ nb, float* __restrict__ out)
{
    __shared__ float tA[32][97];
    __shared__ float tB[32][97];
    __shared__ float ps[4][8][32];
    __shared__ float stat[4][32];

    int blk = blockIdx.x;
    int h = blk & 31;
    int bs = blk >> 5;
    int so = bs & 1;
    int b = bs >> 1;
    int tid = (int)threadIdx.x;

    auto Y = [&](int g) { return yssT + (size_t)(b * 12 + g) * L_LEN * C_DIM; };
    const float* Y0 = Y(so);
    const float* Y0r = Y(6 + so);
    const float* Y1 = Y(3 + so);
    const float* Y1r = Y(9 + so);

#pragma unroll 2
    for (int it = 0; it < 24; ++it) {
        int idx = tid + it * 256;
        int c = idx % 96, rest = idx / 96;
        int w = rest >> 1, par = rest & 1;
        int a0 = h * 64 + rest;
        int a1 = w * 64 + 2 * h + par;
        float v = Y0[(size_t)a0 * C_DIM + c] + Y0r[(size_t)(2047 - a0) * C_DIM + c]
                + Y1[(size_t)a1 * C_DIM + c] + Y1r[(size_t)(2047 - a1) * C_DIM + c];
        if (par) tA[w][c] = v; else tB[w][c] = v;
    }
    __syncthreads();

    int w = tid & 31, cg = tid >> 5;
    float sA = 0, qA = 0, sB = 0, qB = 0;
#pragma unroll
    for (int j = 0; j < 12; ++j) {
        float yv = tA[w][cg * 12 + j], dv = tB[w][cg * 12 + j];
        sA += yv; qA += yv * yv; sB += dv; qB += dv * dv;
    }
    ps[0][cg][w] = sA; ps[1][cg][w] = qA; ps[2][cg][w] = sB; ps[3][cg][w] = qB;
    __syncthreads();
    if (tid < 32) {
        int ww = tid;
        float t0 = 0, t1 = 0, t2 = 0, t3 = 0;
#pragma unroll
        for (int q = 0; q < 8; ++q) {
            t0 += ps[0][q][ww]; t1 += ps[1][q][ww];
            t2 += ps[2][q][ww]; t3 += ps[3][q][ww];
        }
        float muA = t0 * (1.f / 96.f), eqA = t1 * (1.f / 96.f);
        float muB = t2 * (1.f / 96.f), eqB = t3 * (1.f / 96.f);
        stat[0][ww] = muA; stat[1][ww] = rsqrtf(eqA - muA * muA + 1e-5f);
        stat[2][ww] = muB; stat[3][ww] = rsqrtf(eqB - muB * muB + 1e-5f);
    }
    __syncthreads();
    size_t obase = (size_t)blk * 3072;
    for (int e = tid; e < 3072; e += 256) {
        int ww = e / 96, c = e % 96;
        float wc = nw[c], bc = nb[c];
        out[obase + e] = (tA[ww][c] - stat[0][ww]) * stat[1][ww] * wc + bc;
        out[2 * 786432 + obase + e] = (tB[ww][c] - stat[2][ww]) * stat[3][ww] * wc + bc;
    }
    __syncthreads();

    const float* Y2 = Y(2);
    const float* Y2r = Y(8);
    const float* Y3 = Y(5);
    const float* Y3r = Y(11);
#pragma unroll 2
    for (int it = 0; it < 12; ++it) {
        int idx = tid + it * 256;
        int c = idx % 96, w2 = idx / 96;
        int a0 = h * 64 + 2 * w2 + so;
        int a1 = w2 * 64 + 2 * h + so;
        float v = Y2[(size_t)a0 * C_DIM + c] + Y2r[(size_t)(2047 - a0) * C_DIM + c]
                + Y3[(size_t)a1 * C_DIM + c] + Y3r[(size_t)(2047 - a1) * C_DIM + c];
        tA[w2][c] = v;
    }
    __syncthreads();
    float sC = 0, qC = 0;
#pragma unroll
    for (int j = 0; j < 12; ++j) {
        float v = tA[w][cg * 12 + j];
        sC += v; qC += v * v;
    }
    ps[0][cg][w] = sC; ps[1][cg][w] = qC;
    __syncthreads();
    if (tid < 32) {
        int ww = tid;
        float t0 = 0, t1 = 0;
#pragma unroll
        for (int q = 0; q < 8; ++q) { t0 += ps[0][q][ww]; t1 += ps[1][q][ww]; }
        float mu = t0 * (1.f / 96.f), eq = t1 * (1.f / 96.f);
        stat[0][ww] = mu; stat[1][ww] = rsqrtf(eq - mu * mu + 1e-5f);
    }
    __syncthreads();
    for (int e = tid; e < 3072; e += 256) {
        int ww = e / 96, c = e % 96;
        out[786432 + obase + e] = (tA[ww][c] - stat[0][ww]) * stat[1][ww] * nw[c] + nb[c];
    }
}

extern "C" void kernel_launch(void* const* d_in, const int* in_sizes, int n_in,
                              void* d_out, int out_size, void* d_ws, size_t ws_size,
                              hipStream_t stream)
{
    const float* x = (const float*)d_in[0];
    const float* xpw = (const float*)d_in[1];
    const float* dtw = (const float*)d_in[2];
    const float* dtb = (const float*)d_in[3];
    const float* A_logs = (const float*)d_in[4];
    const float* Ds = (const float*)d_in[5];
    const float* nw = (const float*)d_in[6];
    const float* nb = (const float*)d_in[7];
    float* out = (float*)d_out;

    float* ws = (float*)d_ws;
    float* deltaT = ws;                // SZ_DELTA
    float* Bsw = deltaT + SZ_DELTA;    // SZ_BC
    float* Csw = Bsw + SZ_BC;          // SZ_BC
    float* u6T = Csw + SZ_BC;          // SZ_U6
    float* yssT = u6T + SZ_U6;         // SZ_Y (xT+wpad aliased: dead before scanC)
    float* xT = yssT;                  // SZ_X (alias)
    float* wpad = yssT + SZ_X;         // SZ_WPAD (alias)
    float* hend = yssT + SZ_Y;         // SZ_H (becomes hstart in place)
    float* Sbuf = hend + SZ_H;         // SZ_S

    k0_xT<<<dim3(768), dim3(256), 0, stream>>>(x, xT);
    k0b_padw<<<dim3(180), dim3(256), 0, stream>>>(xpw, wpad);
    k1_proj<<<dim3(48 * 32), dim3(256), 0, stream>>>(x, xT, wpad, dtw, dtb, deltaT, Bsw, Csw, u6T);
    k2_scanA<<<dim3(48 * 32), dim3(192), 0, stream>>>(deltaT, Bsw, u6T, A_logs, hend, Sbuf);
    k2_fix<<<dim3(288), dim3(256), 0, stream>>>(Sbuf, A_logs, hend);
    k2_scanC<<<dim3(48 * 32), dim3(192), 0, stream>>>(deltaT, Bsw, Csw, u6T, A_logs, Ds, hend, yssT);
    k3_out<<<dim3(256), dim3(256), 0, stream>>>(yssT, nw, nb, out);
}

// Round 19
// 128.277 us; speedup vs baseline: 1.3605x; 1.0385x over previous
//
#include <hip/hip_runtime.h>
#include <math.h>

typedef float f4 __attribute__((ext_vector_type(4)));
typedef float f2 __attribute__((ext_vector_type(2)));

#define L_LEN 2048
#define C_DIM 96
#define N_DIM 16
#define R_DIM 6
#define G_DIM 12
#define B_DIM 4
#define NCHUNK 64
#define CLEN 32
#define BGC (B_DIM * G_DIM * C_DIM) // 4608
#define VS 136                      // Vsh stride (f4-aligned)

// workspace layout (floats)
#define SZ_DELTA (B_DIM * G_DIM * L_LEN * C_DIM) // 9437184
#define SZ_BC (B_DIM * G_DIM * N_DIM * L_LEN)    // 1572864
#define SZ_U6 (B_DIM * 6 * C_DIM * L_LEN)        // 4718592
#define SZ_Y (B_DIM * G_DIM * C_DIM * L_LEN)     // 9437184
#define SZ_H (BGC * NCHUNK * N_DIM)              // 4718592
#define SZ_S (BGC * NCHUNK)                      // 294912
#define SZ_X (B_DIM * 2 * C_DIM * 1024)          // 786432
#define SZ_WPAD (G_DIM * 40 * C_DIM)             // 46080

__device__ __forceinline__ float fexp2(float x) { return __builtin_amdgcn_exp2f(x); }
__device__ __forceinline__ f2 pkfma(f2 a, f2 b, f2 c) { return __builtin_elementwise_fma(a, b, c); }

__device__ __forceinline__ float softplus_f(float x)
{
    float sp = __logf(1.f + __expf(x));
    return (x > 20.f) ? x : sp;
}

// ---------------- K0: transpose x (H<->W) for odd-k coalescing ----------------
__global__ __launch_bounds__(256) void k0_xT(
    const float* __restrict__ x, float* __restrict__ xT)
{
    __shared__ float t[32][33];
    int img = blockIdx.x;
    const float* src = x + (size_t)img * 1024;
    float* dst = xT + (size_t)img * 1024;
    int tx = threadIdx.x & 31, ty = threadIdx.x >> 5;
#pragma unroll
    for (int r = 0; r < 32; r += 8) t[ty + r][tx] = src[(ty + r) * 32 + tx];
    __syncthreads();
#pragma unroll
    for (int r = 0; r < 32; r += 8) dst[(ty + r) * 32 + tx] = t[tx][ty + r];
}

// ---------------- K0b: zero-pad x_proj_weight rows 38->40 ----------------
__global__ __launch_bounds__(256) void k0b_padw(
    const float* __restrict__ xpw, float* __restrict__ wpad)
{
    int i = blockIdx.x * 256 + (int)threadIdx.x;
    if (i >= G_DIM * 40 * C_DIM) return;
    int g = i / (40 * C_DIM);
    int rem = i - g * 40 * C_DIM;
    int p = rem / C_DIM, c = rem - (rem / C_DIM) * C_DIM;
    wpad[i] = (p < 38) ? xpw[((size_t)g * 38 + p) * C_DIM + c] : 0.f;
}

// ---------------- K1: cross-scan gather + projection, pk over l-pairs ----------------
// grid 768 = 48 (b,g) x 16 tiles of 128 l; block 256 = 64 lanes (l-pairs) x 4 p-groups.
__global__ __launch_bounds__(256) void k1_proj(
    const float* __restrict__ x, const float* __restrict__ xT,
    const float* __restrict__ wpad, const float* __restrict__ dtw,
    const float* __restrict__ dtb,
    float* __restrict__ deltaT, float* __restrict__ Bsw,
    float* __restrict__ Csw, float* __restrict__ u6T)
{
    __shared__ char smem[C_DIM * VS * 4]; // union: Vsh then Psh
    float* Vsh = (float*)smem;            // [c][VS], 128 l valid
    float (*Psh)[132] = (float(*)[132])smem; // [40][132], 128 l valid

    int blk = blockIdx.x;        // bks*16 + ltile
    int ltile = blk & 15;
    int bks = blk >> 4;          // 0..47 = b*12+g
    int g = bks % G_DIM;
    int b = bks / G_DIM;
    const bool rev = (g >= 6);
    int gu = rev ? (g - 6) : g;
    int k = gu / 3, s = gu % 3;
    int l0 = ltile * 128;
    int bg = b * G_DIM + g;
    int tid = (int)threadIdx.x;

    const float* xb = (k ? xT : x) + (size_t)b * 2 * C_DIM * 1024;

    // ---- stage V[c][ll] in OUTPUT-l space (reversal folded into pp + shuffle) ----
#pragma unroll
    for (int j = 0; j < 12; ++j) {
        int e = tid + j * 256;       // < 3072
        int c = e >> 5;
        int llq = (e & 31) * 4;
        int pp = rev ? (1022 - ((l0 + llq) >> 1)) : ((l0 + llq) >> 1);
        f2 x0 = *(const f2*)(xb + (size_t)c * 1024 + pp);
        f2 x1 = *(const f2*)(xb + (size_t)(C_DIM + c) * 1024 + pp);
        f4 v;
        if (!rev) {
            if (s == 2)      { v[0] = x0.x; v[1] = x1.x; v[2] = x0.y; v[3] = x1.y; }
            else if (s == 1) { v[0] = x1.x - x0.x; v[1] = x1.x; v[2] = x1.y - x0.y; v[3] = x1.y; }
            else             { v[0] = x0.x - x1.x; v[1] = x0.x; v[2] = x0.y - x1.y; v[3] = x0.y; }
        } else {
            if (s == 2)      { v[0] = x1.y; v[1] = x0.y; v[2] = x1.x; v[3] = x0.x; }
            else if (s == 1) { v[0] = x1.y; v[1] = x1.y - x0.y; v[2] = x1.x; v[3] = x1.x - x0.x; }
            else             { v[0] = x0.y; v[1] = x0.y - x1.y; v[2] = x0.x; v[3] = x0.x - x1.x; }
        }
        *(f4*)(Vsh + c * VS + llq) = v;
    }
    __syncthreads();

    // ---- u6T[b6g][l][c] (g<6 only; coalesced f4) ----
    if (!rev) {
        size_t ub = ((size_t)(b * 6 + g) * L_LEN + l0) * C_DIM;
#pragma unroll
        for (int j = 0; j < 12; ++j) {
            int e = tid + j * 256;   // < 3072
            int lidx = e / 24;       // 0..127
            int c4 = (e - lidx * 24) * 4;
            f4 v = { Vsh[(c4 + 0) * VS + lidx], Vsh[(c4 + 1) * VS + lidx],
                     Vsh[(c4 + 2) * VS + lidx], Vsh[(c4 + 3) * VS + lidx] };
            *(f4*)(u6T + ub + (size_t)lidx * C_DIM + c4) = v;
        }
    }

    // ---- register GEMM: 10 p-rows x l-pair per thread (pk-fma, scalar-weight broadcast) ----
    int ll = tid & 63;               // l-pair index: covers l = 2*ll, 2*ll+1
    int P0 = __builtin_amdgcn_readfirstlane((tid >> 6) * 10);
    const float* wp = wpad + (size_t)g * 3840 + (size_t)P0 * C_DIM;

    f2 acc2[10];
#pragma unroll
    for (int p = 0; p < 10; ++p) acc2[p] = (f2){0.f, 0.f};

    for (int cb = 0; cb < C_DIM; cb += 8) {
        f2 vc2[8];
#pragma unroll
        for (int i = 0; i < 8; ++i)
            vc2[i] = *(const f2*)(Vsh + (cb + i) * VS + 2 * ll);
#pragma unroll
        for (int p = 0; p < 10; ++p) {
#pragma unroll
            for (int q = 0; q < 2; ++q) {
                f4 w = *(const f4*)(wp + p * C_DIM + cb + q * 4);
#pragma unroll
                for (int i = 0; i < 4; ++i)
                    acc2[p] = pkfma((f2){w[i], w[i]}, vc2[q * 4 + i], acc2[p]);
            }
        }
    }

    // ---- transpose via Psh (union over Vsh), stores + delta epilogue ----
    __syncthreads();   // all Vsh reads done before overwrite
#pragma unroll
    for (int p = 0; p < 10; ++p) {
        Psh[P0 + p][2 * ll] = acc2[p].x;
        Psh[P0 + p][2 * ll + 1] = acc2[p].y;
    }
    __syncthreads();
#pragma unroll
    for (int half = 0; half < 2; ++half) {
        int q = tid & 3, lx = (tid >> 2) + half * 64;
        f4 bv = { Psh[6 + q * 4 + 0][lx], Psh[6 + q * 4 + 1][lx],
                  Psh[6 + q * 4 + 2][lx], Psh[6 + q * 4 + 3][lx] };
        *(f4*)(Bsw + ((size_t)bg * L_LEN + l0 + lx) * N_DIM + q * 4) = bv;
        f4 cv = { Psh[22 + q * 4 + 0][lx], Psh[22 + q * 4 + 1][lx],
                  Psh[22 + q * 4 + 2][lx], Psh[22 + q * 4 + 3][lx] };
        *(f4*)(Csw + ((size_t)bg * L_LEN + l0 + lx) * N_DIM + q * 4) = cv;
    }
    const float* wdg = dtw + (size_t)g * C_DIM * R_DIM;
    const float* biasg = dtb + g * C_DIM;
    size_t db = ((size_t)bg * L_LEN + l0) * C_DIM;
#pragma unroll
    for (int it = 0; it < 24; ++it) {
        int e = tid + it * 256;          // < 6144 = 64 l-pairs x 96 c
        int lp = e / 96, c = e - (e / 96) * 96;
        const float* wrow = wdg + c * R_DIM;
        f2 ds2 = { biasg[c], biasg[c] };
#pragma unroll
        for (int r = 0; r < R_DIM; ++r) {
            f2 pv = { Psh[r][2 * lp], Psh[r][2 * lp + 1] };
            ds2 = pkfma((f2){wrow[r], wrow[r]}, pv, ds2);
        }
        deltaT[db + (size_t)(2 * lp) * C_DIM + c] = softplus_f(ds2.x);
        deltaT[db + (size_t)(2 * lp + 1) * C_DIM + c] = softplus_f(ds2.y);
    }
}

// ---------------- K2: chunk-parallel scan (R12 version) ----------------
__global__ __launch_bounds__(192) void k2_scanA(
    const float* __restrict__ deltaT, const float* __restrict__ Bsw,
    const float* __restrict__ u6T, const float* __restrict__ A_logs,
    float* __restrict__ hend, float* __restrict__ Sbuf)
{
    __shared__ f4 Bsh[256];     // 64 l x 16 n
    int blk = blockIdx.x;
    int chgrp = blk & 31;
    int bg = blk >> 5;
    int g = bg % G_DIM;
    int b = bg / G_DIM;
    int tid = (int)threadIdx.x;

    const f4* Bg = (const f4*)(Bsw + ((size_t)bg * L_LEN + chgrp * 64) * N_DIM);
    for (int i = tid; i < 256; i += 192) Bsh[i] = Bg[i];
    __syncthreads();

    int chl = tid / 96;
    int c = tid % 96;
    int ch = chgrp * 2 + chl;
    int bgc = bg * C_DIM + c;
    const bool rev = (g >= 6);
    int gu = rev ? (g - 6) : g;

    float a2[N_DIM];
    {
        const f4* Ap = (const f4*)(A_logs + ((size_t)g * C_DIM + c) * N_DIM);
        f4 Av[4] = { Ap[0], Ap[1], Ap[2], Ap[3] };
#pragma unroll
        for (int n = 0; n < N_DIM; ++n)
            a2[n] = -__expf(Av[n >> 2][n & 3]) * 1.44269504f;
    }

    const int LOFF = ch * CLEN;
    const float* dp = deltaT + ((size_t)bg * L_LEN + LOFF) * C_DIM + c;
    const float* up;
    int us;
    if (rev) { up = u6T + ((size_t)(b * 6 + gu) * L_LEN + (2047 - LOFF)) * C_DIM + c; us = -C_DIM; }
    else     { up = u6T + ((size_t)(b * 6 + gu) * L_LEN + LOFF) * C_DIM + c; us = C_DIM; }

    float h[N_DIM];
#pragma unroll
    for (int n = 0; n < N_DIM; ++n) h[n] = 0.f;
    float S = 0.f;

    float dbuf[4], ubuf[4];
#pragma unroll
    for (int j = 0; j < 4; ++j) { dbuf[j] = dp[j * C_DIM]; ubuf[j] = up[j * us]; }

    for (int jj = 0; jj < CLEN; jj += 4) {
        int nx = (jj + 4 < CLEN) ? jj + 4 : jj;
        float dn[4], un[4];
#pragma unroll
        for (int j = 0; j < 4; ++j) { dn[j] = dp[(nx + j) * C_DIM]; un[j] = up[(nx + j) * us]; }
#pragma unroll
        for (int j = 0; j < 4; ++j) {
            int li = chl * CLEN + jj + j;
            float d = dbuf[j];
            S += d;
            float du = d * ubuf[j];
            const f4* Bl = Bsh + (size_t)li * 4;
            f4 Bv[4] = { Bl[0], Bl[1], Bl[2], Bl[3] };
#pragma unroll
            for (int n = 0; n < N_DIM; ++n) {
                float e = fexp2(d * a2[n]);
                h[n] = fmaf(h[n], e, du * Bv[n >> 2][n & 3]);
            }
        }
#pragma unroll
        for (int j = 0; j < 4; ++j) { dbuf[j] = dn[j]; ubuf[j] = un[j]; }
    }
    float* hp = hend + ((size_t)bgc * NCHUNK + ch) * N_DIM;
#pragma unroll
    for (int q = 0; q < 4; ++q) {
        f4 hv = { h[q * 4], h[q * 4 + 1], h[q * 4 + 2], h[q * 4 + 3] };
        *(f4*)(hp + q * 4) = hv;
    }
    Sbuf[(size_t)bgc * NCHUNK + ch] = S;
}

// Pass B: compose chunk propagators; hend -> hstart IN PLACE (P recomputed from S).
__global__ __launch_bounds__(256) void k2_fix(
    const float* __restrict__ Sbuf, const float* __restrict__ A_logs, float* hh)
{
    int t = blockIdx.x * 256 + (int)threadIdx.x; // 73728
    int n = t & 15;
    int bgc = t >> 4;
    int c = bgc % C_DIM;
    int g = (bgc / C_DIM) % G_DIM;
    float a2 = -__expf(A_logs[((size_t)g * C_DIM + c) * N_DIM + n]) * 1.44269504f;
    const float* Sp = Sbuf + (size_t)bgc * NCHUNK;
    float h = 0.f;
    for (int ch = 0; ch < NCHUNK; ++ch) {
        size_t idx = ((size_t)bgc * NCHUNK + ch) * N_DIM + n;
        float he = hh[idx];
        float P = fexp2(a2 * Sp[ch]);
        hh[idx] = h;
        h = fmaf(h, P, he);
    }
}

// Pass C: exact recurrence from hstart, writes yT [bg][l][c] (+Ds*u folded).
__global__ __launch_bounds__(192) void k2_scanC(
    const float* __restrict__ deltaT, const float* __restrict__ Bsw,
    const float* __restrict__ Csw, const float* __restrict__ u6T,
    const float* __restrict__ A_logs, const float* __restrict__ Ds,
    const float* __restrict__ hstart, float* __restrict__ yssT)
{
    __shared__ f4 Bsh[256];
    __shared__ f4 Csh[256];
    int blk = blockIdx.x;
    int chgrp = blk & 31;
    int bg = blk >> 5;
    int g = bg % G_DIM;
    int b = bg / G_DIM;
    int tid = (int)threadIdx.x;

    const f4* Bg = (const f4*)(Bsw + ((size_t)bg * L_LEN + chgrp * 64) * N_DIM);
    const f4* Cg = (const f4*)(Csw + ((size_t)bg * L_LEN + chgrp * 64) * N_DIM);
    for (int i = tid; i < 256; i += 192) { Bsh[i] = Bg[i]; Csh[i] = Cg[i]; }
    __syncthreads();

    int chl = tid / 96;
    int c = tid % 96;
    int ch = chgrp * 2 + chl;
    int bgc = bg * C_DIM + c;
    const bool rev = (g >= 6);
    int gu = rev ? (g - 6) : g;

    float a2[N_DIM];
    {
        const f4* Ap = (const f4*)(A_logs + ((size_t)g * C_DIM + c) * N_DIM);
        f4 Av[4] = { Ap[0], Ap[1], Ap[2], Ap[3] };
#pragma unroll
        for (int n = 0; n < N_DIM; ++n)
            a2[n] = -__expf(Av[n >> 2][n & 3]) * 1.44269504f;
    }
    float dsc = Ds[g * C_DIM + c];

    const int LOFF = ch * CLEN;
    const float* dp = deltaT + ((size_t)bg * L_LEN + LOFF) * C_DIM + c;
    const float* up;
    int us;
    if (rev) { up = u6T + ((size_t)(b * 6 + gu) * L_LEN + (2047 - LOFF)) * C_DIM + c; us = -C_DIM; }
    else     { up = u6T + ((size_t)(b * 6 + gu) * L_LEN + LOFF) * C_DIM + c; us = C_DIM; }
    float* yp = yssT + ((size_t)bg * L_LEN + LOFF) * C_DIM + c;

    float h[N_DIM];
    {
        const f4* Hp = (const f4*)(hstart + ((size_t)bgc * NCHUNK + ch) * N_DIM);
        f4 Hv[4] = { Hp[0], Hp[1], Hp[2], Hp[3] };
#pragma unroll
        for (int n = 0; n < N_DIM; ++n) h[n] = Hv[n >> 2][n & 3];
    }

    float dbuf[4], ubuf[4];
#pragma unroll
    for (int j = 0; j < 4; ++j) { dbuf[j] = dp[j * C_DIM]; ubuf[j] = up[j * us]; }

    for (int jj = 0; jj < CLEN; jj += 4) {
        int nx = (jj + 4 < CLEN) ? jj + 4 : jj;
        float dn[4], un[4];
#pragma unroll
        for (int j = 0; j < 4; ++j) { dn[j] = dp[(nx + j) * C_DIM]; un[j] = up[(nx + j) * us]; }
#pragma unroll
        for (int j = 0; j < 4; ++j) {
            int li = chl * CLEN + jj + j;
            float d = dbuf[j];
            float uu = ubuf[j];
            float du = d * uu;
            const f4* Bl = Bsh + (size_t)li * 4;
            const f4* Cl = Csh + (size_t)li * 4;
            f4 Bv[4] = { Bl[0], Bl[1], Bl[2], Bl[3] };
            f4 Cv[4] = { Cl[0], Cl[1], Cl[2], Cl[3] };
            float y0 = dsc * uu, y1 = 0.f, y2 = 0.f, y3 = 0.f;
#pragma unroll
            for (int q = 0; q < 4; ++q) {
                float e0 = fexp2(d * a2[q * 4 + 0]);
                float e1 = fexp2(d * a2[q * 4 + 1]);
                float e2 = fexp2(d * a2[q * 4 + 2]);
                float e3 = fexp2(d * a2[q * 4 + 3]);
                h[q * 4 + 0] = fmaf(h[q * 4 + 0], e0, du * Bv[q][0]);
                h[q * 4 + 1] = fmaf(h[q * 4 + 1], e1, du * Bv[q][1]);
                h[q * 4 + 2] = fmaf(h[q * 4 + 2], e2, du * Bv[q][2]);
                h[q * 4 + 3] = fmaf(h[q * 4 + 3], e3, du * Bv[q][3]);
                y0 = fmaf(h[q * 4 + 0], Cv[q][0], y0);
                y1 = fmaf(h[q * 4 + 1], Cv[q][1], y1);
                y2 = fmaf(h[q * 4 + 2], Cv[q][2], y2);
                y3 = fmaf(h[q * 4 + 3], Cv[q][3], y3);
            }
            yp[(jj + j) * C_DIM] = (y0 + y1) + (y2 + y3);
        }
#pragma unroll
        for (int j = 0; j < 4; ++j) { dbuf[j] = dn[j]; ubuf[j] = un[j]; }
    }
}

// ---------------- K3: fold (un-scan) + LayerNorm, fused ([l][c] input) ----------------
__global__ __launch_bounds__(256) void k3_out(
    const float* __restrict__ yssT, const float* __restrict__ nw,
    const float* __restrict__ nb, float* __restrict__ out)
{
    __shared__ float tA[32][97];
    __shared__ float tB[32][97];
    __shared__ float ps[4][8][32];
    __shared__ float stat[4][32];

    int blk = blockIdx.x;
    int h = blk & 31;
    int bs = blk >> 5;
    int so = bs & 1;
    int b = bs >> 1;
    int tid = (int)threadIdx.x;

    auto Y = [&](int g) { return yssT + (size_t)(b * 12 + g) * L_LEN * C_DIM; };
    const float* Y0 = Y(so);
    const float* Y0r = Y(6 + so);
    const float* Y1 = Y(3 + so);
    const float* Y1r = Y(9 + so);

#pragma unroll 2
    for (int it = 0; it < 24; ++it) {
        int idx = tid + it * 256;
        int c = idx % 96, rest = idx / 96;
        int w = rest >> 1, par = rest & 1;
        int a0 = h * 64 + rest;
        int a1 = w * 64 + 2 * h + par;
        float v = Y0[(size_t)a0 * C_DIM + c] + Y0r[(size_t)(2047 - a0) * C_DIM + c]
                + Y1[(size_t)a1 * C_DIM + c] + Y1r[(size_t)(2047 - a1) * C_DIM + c];
        if (par) tA[w][c] = v; else tB[w][c] = v;
    }
    __syncthreads();

    int w = tid & 31, cg = tid >> 5;
    float sA = 0, qA = 0, sB = 0, qB = 0;
#pragma unroll
    for (int j = 0; j < 12; ++j) {
        float yv = tA[w][cg * 12 + j], dv = tB[w][cg * 12 + j];
        sA += yv; qA += yv * yv; sB += dv; qB += dv * dv;
    }
    ps[0][cg][w] = sA; ps[1][cg][w] = qA; ps[2][cg][w] = sB; ps[3][cg][w] = qB;
    __syncthreads();
    if (tid < 32) {
        int ww = tid;
        float t0 = 0, t1 = 0, t2 = 0, t3 = 0;
#pragma unroll
        for (int q = 0; q < 8; ++q) {
            t0 += ps[0][q][ww]; t1 += ps[1][q][ww];
            t2 += ps[2][q][ww]; t3 += ps[3][q][ww];
        }
        float muA = t0 * (1.f / 96.f), eqA = t1 * (1.f / 96.f);
        float muB = t2 * (1.f / 96.f), eqB = t3 * (1.f / 96.f);
        stat[0][ww] = muA; stat[1][ww] = rsqrtf(eqA - muA * muA + 1e-5f);
        stat[2][ww] = muB; stat[3][ww] = rsqrtf(eqB - muB * muB + 1e-5f);
    }
    __syncthreads();
    size_t obase = (size_t)blk * 3072;
    for (int e = tid; e < 3072; e += 256) {
        int ww = e / 96, c = e % 96;
        float wc = nw[c], bc = nb[c];
        out[obase + e] = (tA[ww][c] - stat[0][ww]) * stat[1][ww] * wc + bc;
        out[2 * 786432 + obase + e] = (tB[ww][c] - stat[2][ww]) * stat[3][ww] * wc + bc;
    }
    __syncthreads();

    const float* Y2 = Y(2);
    const float* Y2r = Y(8);
    const float* Y3 = Y(5);
    const float* Y3r = Y(11);
#pragma unroll 2
    for (int it = 0; it < 12; ++it) {
        int idx = tid + it * 256;
        int c = idx % 96, w2 = idx / 96;
        int a0 = h * 64 + 2 * w2 + so;
        int a1 = w2 * 64 + 2 * h + so;
        float v = Y2[(size_t)a0 * C_DIM + c] + Y2r[(size_t)(2047 - a0) * C_DIM + c]
                + Y3[(size_t)a1 * C_DIM + c] + Y3r[(size_t)(2047 - a1) * C_DIM + c];
        tA[w2][c] = v;
    }
    __syncthreads();
    float sC = 0, qC = 0;
#pragma unroll
    for (int j = 0; j < 12; ++j) {
        float v = tA[w][cg * 12 + j];
        sC += v; qC += v * v;
    }
    ps[0][cg][w] = sC; ps[1][cg][w] = qC;
    __syncthreads();
    if (tid < 32) {
        int ww = tid;
        float t0 = 0, t1 = 0;
#pragma unroll
        for (int q = 0; q < 8; ++q) { t0 += ps[0][q][ww]; t1 += ps[1][q][ww]; }
        float mu = t0 * (1.f / 96.f), eq = t1 * (1.f / 96.f);
        stat[0][ww] = mu; stat[1][ww] = rsqrtf(eq - mu * mu + 1e-5f);
    }
    __syncthreads();
    for (int e = tid; e < 3072; e += 256) {
        int ww = e / 96, c = e % 96;
        out[786432 + obase + e] = (tA[ww][c] - stat[0][ww]) * stat[1][ww] * nw[c] + nb[c];
    }
}

extern "C" void kernel_launch(void* const* d_in, const int* in_sizes, int n_in,
                              void* d_out, int out_size, void* d_ws, size_t ws_size,
                              hipStream_t stream)
{
    const float* x = (const float*)d_in[0];
    const float* xpw = (const float*)d_in[1];
    const float* dtw = (const float*)d_in[2];
    const float* dtb = (const float*)d_in[3];
    const float* A_logs = (const float*)d_in[4];
    const float* Ds = (const float*)d_in[5];
    const float* nw = (const float*)d_in[6];
    const float* nb = (const float*)d_in[7];
    float* out = (float*)d_out;

    float* ws = (float*)d_ws;
    float* deltaT = ws;                // SZ_DELTA
    float* Bsw = deltaT + SZ_DELTA;    // SZ_BC
    float* Csw = Bsw + SZ_BC;          // SZ_BC
    float* u6T = Csw + SZ_BC;          // SZ_U6
    float* yssT = u6T + SZ_U6;         // SZ_Y (xT+wpad aliased: dead before scanC)
    float* xT = yssT;                  // SZ_X (alias)
    float* wpad = yssT + SZ_X;         // SZ_WPAD (alias)
    float* hend = yssT + SZ_Y;         // SZ_H (becomes hstart in place)
    float* Sbuf = hend + SZ_H;         // SZ_S

    k0_xT<<<dim3(768), dim3(256), 0, stream>>>(x, xT);
    k0b_padw<<<dim3(180), dim3(256), 0, stream>>>(xpw, wpad);
    k1_proj<<<dim3(48 * 16), dim3(256), 0, stream>>>(x, xT, wpad, dtw, dtb, deltaT, Bsw, Csw, u6T);
    k2_scanA<<<dim3(48 * 32), dim3(192), 0, stream>>>(deltaT, Bsw, u6T, A_logs, hend, Sbuf);
    k2_fix<<<dim3(288), dim3(256), 0, stream>>>(Sbuf, A_logs, hend);
    k2_scanC<<<dim3(48 * 32), dim3(192), 0, stream>>>(deltaT, Bsw, Csw, u6T, A_logs, Ds, hend, yssT);
    k3_out<<<dim3(256), dim3(256), 0, stream>>>(yssT, nw, nb, out);
}